// Round 1
// baseline (10477.482 us; speedup 1.0000x reference)
//
#include <hip/hip_runtime.h>
#include <hip/hip_bf16.h>
#include <math.h>

// Problem constants
// B=16, S=256, E=256, H=256, V=50000, L=9
#define BB 16
#define SS 256
#define EE 256
#define HH 256
#define LL 9
#define ROWS (BB*SS)      // 4096
#define G4 (4*HH)         // 1024 gate rows per direction

// ---------------------------------------------------------------------------
// Embedding gather: xA[row][e] = embedding[ids[row]][e]
__global__ __launch_bounds__(256) void embed_kernel(
    const int* __restrict__ ids, const float* __restrict__ emb,
    float* __restrict__ x) {
  int row = blockIdx.x;
  int id = ids[row];
  x[(size_t)row * EE + threadIdx.x] = emb[(size_t)id * EE + threadIdx.x];
}

// ---------------------------------------------------------------------------
// Transpose w_hh for one layer: w[dir][r][k] (1024x256) -> wt[dir][k][r] (256x1024)
__global__ __launch_bounds__(256) void transpose_whh(
    const float* __restrict__ w, float* __restrict__ wt) {
  int dir = blockIdx.z;
  int r0 = blockIdx.x * 32;
  int k0 = blockIdx.y * 32;
  __shared__ float tl[32][33];
  int tx = threadIdx.x, ty = threadIdx.y;  // 32 x 8
  const float* wp = w + (size_t)dir * G4 * HH;
  float* wtp = wt + (size_t)dir * HH * G4;
#pragma unroll
  for (int j = 0; j < 32; j += 8)
    tl[ty + j][tx] = wp[(size_t)(r0 + ty + j) * HH + k0 + tx];
  __syncthreads();
#pragma unroll
  for (int j = 0; j < 32; j += 8)
    wtp[(size_t)(k0 + ty + j) * G4 + r0 + tx] = tl[tx][ty + j];
}

// ---------------------------------------------------------------------------
// Input projection GEMM (NT): C[dir][m][n] = sum_k A[m][k]*B[dir][n][k] + bias
// A: ROWSxK row-major. B: per-dir 1024xK row-major. C: [2][ROWS][1024].
// bias: [2][2][1024] (b_ih + b_hh added together)
__global__ __launch_bounds__(256) void gemm_xg(
    const float* __restrict__ A, int K,
    const float* __restrict__ B, int dirStrideB,
    const float* __restrict__ bias,
    float* __restrict__ C) {
  int dir = blockIdx.z;
  const float* Bp = B + (size_t)dir * dirStrideB;
  const float* bi = bias + (size_t)dir * 2 * G4;
  float* Cp = C + (size_t)dir * ROWS * G4;
  int n0 = blockIdx.x * 64, m0 = blockIdx.y * 64;
  int tid = threadIdx.x;
  int tx = tid & 15, ty = tid >> 4;
  __shared__ float As[16][68];
  __shared__ float Bs[16][68];
  float acc[4][4] = {{0.f}};
  int lm = tid >> 2;             // 0..63
  int lk = (tid & 3) * 4;        // 0,4,8,12
  for (int k0 = 0; k0 < K; k0 += 16) {
    float4 av = *(const float4*)&A[(size_t)(m0 + lm) * K + k0 + lk];
    float4 bv = *(const float4*)&Bp[(size_t)(n0 + lm) * K + k0 + lk];
    As[lk + 0][lm] = av.x; As[lk + 1][lm] = av.y;
    As[lk + 2][lm] = av.z; As[lk + 3][lm] = av.w;
    Bs[lk + 0][lm] = bv.x; Bs[lk + 1][lm] = bv.y;
    Bs[lk + 2][lm] = bv.z; Bs[lk + 3][lm] = bv.w;
    __syncthreads();
#pragma unroll
    for (int kk = 0; kk < 16; ++kk) {
      float4 a = *(const float4*)&As[kk][ty * 4];
      float4 b4 = *(const float4*)&Bs[kk][tx * 4];
      acc[0][0] += a.x * b4.x; acc[0][1] += a.x * b4.y;
      acc[0][2] += a.x * b4.z; acc[0][3] += a.x * b4.w;
      acc[1][0] += a.y * b4.x; acc[1][1] += a.y * b4.y;
      acc[1][2] += a.y * b4.z; acc[1][3] += a.y * b4.w;
      acc[2][0] += a.z * b4.x; acc[2][1] += a.z * b4.y;
      acc[2][2] += a.z * b4.z; acc[2][3] += a.z * b4.w;
      acc[3][0] += a.w * b4.x; acc[3][1] += a.w * b4.y;
      acc[3][2] += a.w * b4.z; acc[3][3] += a.w * b4.w;
    }
    __syncthreads();
  }
  int n = n0 + tx * 4;
  float4 b0 = *(const float4*)&bi[n];
  float4 b1 = *(const float4*)&bi[G4 + n];
  float bs0 = b0.x + b1.x, bs1 = b0.y + b1.y, bs2 = b0.z + b1.z, bs3 = b0.w + b1.w;
#pragma unroll
  for (int i = 0; i < 4; ++i) {
    float4 v;
    v.x = acc[i][0] + bs0; v.y = acc[i][1] + bs1;
    v.z = acc[i][2] + bs2; v.w = acc[i][3] + bs3;
    *(float4*)&Cp[(size_t)(m0 + ty * 4 + i) * G4 + n] = v;
  }
}

// ---------------------------------------------------------------------------
// LSTM recurrence for one layer, both directions.
// grid = 32 blocks: blockIdx.x = b*2 + dir. block = 1024 threads (one gate row each).
// xg: [2][ROWS][1024] (biases already added). wT: [2][256][1024] transposed w_hh.
// out: [ROWS][512] concat (forward -> cols 0..255, backward -> 256..511)
__global__ __launch_bounds__(1024) void lstm_rec(
    const float* __restrict__ xg, const float* __restrict__ wT,
    float* __restrict__ out) {
  int b = blockIdx.x >> 1;
  int dir = blockIdx.x & 1;
  int r = threadIdx.x;  // gate row 0..1023
  __shared__ float h_sh[HH];
  __shared__ float gates[G4];
  if (r < HH) h_sh[r] = 0.f;
  float c = 0.f;
  __syncthreads();
  const float* wbase = wT + (size_t)dir * HH * G4;
  const float* xgb = xg + ((size_t)dir * ROWS + (size_t)b * SS) * G4;
  for (int t = 0; t < SS; ++t) {
    int pos = dir ? (SS - 1 - t) : t;
    float acc = xgb[(size_t)pos * G4 + r];
#pragma unroll 8
    for (int k = 0; k < HH; k += 4) {
      float4 h4 = *(const float4*)&h_sh[k];
      acc += wbase[(size_t)(k + 0) * G4 + r] * h4.x;
      acc += wbase[(size_t)(k + 1) * G4 + r] * h4.y;
      acc += wbase[(size_t)(k + 2) * G4 + r] * h4.z;
      acc += wbase[(size_t)(k + 3) * G4 + r] * h4.w;
    }
    gates[r] = acc;
    __syncthreads();
    if (r < HH) {
      float ig = gates[r];
      float fg = gates[HH + r];
      float gg = gates[2 * HH + r];
      float og = gates[3 * HH + r];
      float si = 1.f / (1.f + expf(-ig));
      float sf = 1.f / (1.f + expf(-fg));
      float so = 1.f / (1.f + expf(-og));
      c = sf * c + si * tanhf(gg);
      float h = so * tanhf(c);
      h_sh[r] = h;
      out[(size_t)(b * SS + pos) * (2 * HH) + dir * HH + r] = h;
    }
    __syncthreads();
  }
}

// ---------------------------------------------------------------------------
// LayerNorm + 9-way linear. One wave (64 threads) per row.
__global__ __launch_bounds__(64) void ln_logits(
    const float* __restrict__ X, const float* __restrict__ g,
    const float* __restrict__ bt, const float* __restrict__ W,
    const float* __restrict__ lb, float* __restrict__ out) {
  int row = blockIdx.x;
  int lane = threadIdx.x;
  const float* x = X + (size_t)row * 512;
  float v[8];
  float s = 0.f, s2 = 0.f;
#pragma unroll
  for (int i = 0; i < 8; ++i) {
    v[i] = x[lane + 64 * i];
    s += v[i];
    s2 += v[i] * v[i];
  }
#pragma unroll
  for (int off = 32; off; off >>= 1) {
    s += __shfl_down(s, off, 64);
    s2 += __shfl_down(s2, off, 64);
  }
  s = __shfl(s, 0, 64);
  s2 = __shfl(s2, 0, 64);
  float mu = s * (1.f / 512.f);
  float var = s2 * (1.f / 512.f) - mu * mu;
  float rstd = rsqrtf(var + 1e-5f);
  float y[8];
#pragma unroll
  for (int i = 0; i < 8; ++i) {
    int e = lane + 64 * i;
    y[i] = (v[i] - mu) * rstd * g[e] + bt[e];
  }
  for (int l = 0; l < LL; ++l) {
    float p = 0.f;
#pragma unroll
    for (int i = 0; i < 8; ++i) p += y[i] * W[(size_t)l * 512 + lane + 64 * i];
#pragma unroll
    for (int off = 32; off; off >>= 1) p += __shfl_down(p, off, 64);
    if (lane == 0) out[(size_t)row * LL + l] = p + lb[l];
  }
}

// ---------------------------------------------------------------------------
// CRF numerator + denominator + loss. One block of 256 threads.
// Thread layout: b = tid>>4 (16 batches), i = tid&15 (16 lanes per batch group,
// groups live inside one wave -> lockstep, no cross-wave hazards).
__global__ __launch_bounds__(256) void crf_kernel(
    const float* __restrict__ logits, const int* __restrict__ labels,
    const int* __restrict__ mask, const float* __restrict__ cs,
    const float* __restrict__ ce, const float* __restrict__ ct,
    float* __restrict__ loss_out) {
  __shared__ float trans[9][12];
  __shared__ float alpha[2][BB][12];
  __shared__ float numsh[BB];
  __shared__ float res[BB];
  int tid = threadIdx.x;
  int b = tid >> 4;
  int i = tid & 15;
  if (tid < 81) trans[tid / 9][tid % 9] = ct[tid];
  __syncthreads();
  const float* lg = logits + (size_t)b * SS * LL;
  const int* lbp = labels + (size_t)b * SS;
  const int* mk = mask + (size_t)b * SS;

  // ---- numerator (parallel sum over t across 16 lanes of the group)
  float np = 0.f;
  int msum = 0;
  for (int t = i; t < SS; t += 16) {
    msum += mk[t];
    if (t == 0) {
      int l0 = lbp[0];
      np += cs[l0] + lg[l0];
    } else {
      float m = (float)mk[t];
      np += (trans[lbp[t - 1]][lbp[t]] + lg[(size_t)t * LL + lbp[t]]) * m;
    }
  }
#pragma unroll
  for (int off = 8; off; off >>= 1) {
    np += __shfl_down(np, off, 16);
    msum += __shfl_down(msum, off, 16);
  }
  if (i == 0) {
    int last = msum - 1;
    numsh[b] = np + ce[lbp[last]];
  }

  // ---- denominator (forward algorithm, 9 states, double-buffered alpha)
  if (i < LL) alpha[0][b][i] = cs[i] + lg[i];
  int cur = 0;
  for (int t = 1; t < SS; ++t) {
    if (i < LL) {
      float e = lg[(size_t)t * LL + i];
      float av[9];
      float mmax = -1e30f;
#pragma unroll
      for (int p = 0; p < LL; ++p) {
        float vv = alpha[cur][b][p] + trans[p][i];
        av[p] = vv;
        mmax = fmaxf(mmax, vv);
      }
      float ssum = 0.f;
#pragma unroll
      for (int p = 0; p < LL; ++p) ssum += expf(av[p] - mmax);
      float anew = e + mmax + logf(ssum);
      float aold = alpha[cur][b][i];
      alpha[cur ^ 1][b][i] = (mk[t] > 0) ? anew : aold;
    }
    cur ^= 1;
  }
  if (i == 0) {
    float arr[9];
    float m2 = -1e30f;
#pragma unroll
    for (int cc = 0; cc < LL; ++cc) {
      arr[cc] = alpha[cur][b][cc] + ce[cc];
      m2 = fmaxf(m2, arr[cc]);
    }
    float ssd = 0.f;
#pragma unroll
    for (int cc = 0; cc < LL; ++cc) ssd += expf(arr[cc] - m2);
    float denom = m2 + logf(ssd);
    res[b] = numsh[b] - denom;
  }
  __syncthreads();
  if (tid == 0) {
    float Lsum = 0.f;
    for (int b2 = 0; b2 < BB; ++b2) Lsum += res[b2];
    loss_out[0] = -Lsum;
  }
}

// ---------------------------------------------------------------------------
extern "C" void kernel_launch(void* const* d_in, const int* in_sizes, int n_in,
                              void* d_out, int out_size, void* d_ws, size_t ws_size,
                              hipStream_t stream) {
  const int* input_ids = (const int*)d_in[0];
  const int* attn_mask = (const int*)d_in[1];
  const int* labels = (const int*)d_in[2];
  const float* embedding = (const float*)d_in[3];
  const float* w_ih_l0 = (const float*)d_in[4];
  const float* w_ih_rest = (const float*)d_in[5];
  const float* w_hh = (const float*)d_in[6];
  const float* bvec = (const float*)d_in[7];
  const float* ln_g = (const float*)d_in[8];
  const float* ln_b = (const float*)d_in[9];
  const float* lin_w = (const float*)d_in[10];
  const float* lin_b = (const float*)d_in[11];
  const float* crf_start = (const float*)d_in[12];
  const float* crf_end = (const float*)d_in[13];
  const float* crf_trans = (const float*)d_in[14];
  float* out = (float*)d_out;
  float* ws = (float*)d_ws;

  float* xA = ws;                         // 4096*512
  float* xB = xA + (size_t)ROWS * 512;    // 4096*512
  float* xg = xB + (size_t)ROWS * 512;    // 2*4096*1024
  float* wT = xg + (size_t)2 * ROWS * G4; // 2*256*1024

  embed_kernel<<<ROWS, 256, 0, stream>>>(input_ids, embedding, xA);

  float* cur = xA;
  float* nxt = xB;
  for (int l = 0; l < 4; ++l) {
    int K = l ? 512 : 256;
    const float* wih = l ? (w_ih_rest + (size_t)(l - 1) * 2 * G4 * 512) : w_ih_l0;
    transpose_whh<<<dim3(32, 8, 2), dim3(32, 8), 0, stream>>>(
        w_hh + (size_t)l * 2 * G4 * HH, wT);
    gemm_xg<<<dim3(16, 64, 2), 256, 0, stream>>>(
        cur, K, wih, G4 * K, bvec + (size_t)l * 2 * 2 * G4, xg);
    lstm_rec<<<32, 1024, 0, stream>>>(xg, wT, nxt);
    float* tmp = cur; cur = nxt; nxt = tmp;
  }

  ln_logits<<<ROWS, 64, 0, stream>>>(cur, ln_g, ln_b, lin_w, lin_b, out);
  crf_kernel<<<1, 256, 0, stream>>>(out, labels, attn_mask, crf_start, crf_end,
                                    crf_trans, out + (size_t)ROWS * LL);
}

// Round 2
// 9559.776 us; speedup vs baseline: 1.0960x; 1.0960x over previous
//
#include <hip/hip_runtime.h>
#include <hip/hip_bf16.h>
#include <math.h>

// Problem constants: B=16, S=256, E=256, H=256, V=50000, L=9
#define BB 16
#define SS 256
#define EE 256
#define HH 256
#define LL 9
#define ROWS (BB*SS)      // 4096
#define G4 (4*HH)         // 1024 gate rows per direction

typedef __attribute__((ext_vector_type(8))) short short8;   // 8 bf16 = 4 VGPRs
typedef __attribute__((ext_vector_type(4))) float f32x4;    // MFMA acc

// ---------------------------------------------------------------------------
__device__ __forceinline__ unsigned short f2bf(float f) {
  unsigned u = __float_as_uint(f);
  unsigned r = (u + 0x7FFF + ((u >> 16) & 1)) >> 16;  // RNE
  return (unsigned short)r;
}

// ---------------------------------------------------------------------------
// Embedding gather
__global__ __launch_bounds__(256) void embed_kernel(
    const int* __restrict__ ids, const float* __restrict__ emb,
    float* __restrict__ x) {
  int row = blockIdx.x;
  int id = ids[row];
  x[(size_t)row * EE + threadIdx.x] = emb[(size_t)id * EE + threadIdx.x];
}

// ---------------------------------------------------------------------------
// Pack w_hh (one layer) into bf16 MFMA B-fragments.
// wfrag[dir][T(64)][ks(8)][lane(64)][j(8)] = w[dir][n=T*16+(lane&15)][k=ks*32+(lane>>4)*8+j]
__global__ __launch_bounds__(64) void pack_whh(
    const float* __restrict__ w, short* __restrict__ wfrag) {
  int T = blockIdx.x;       // 0..63
  int ks = blockIdx.y;      // 0..7
  int dir = blockIdx.z;     // 0..1
  int lane = threadIdx.x;   // 0..63
  int col = lane & 15, quad = lane >> 4;
  const float* wp = w + (size_t)dir * G4 * HH + (size_t)(T * 16 + col) * HH + ks * 32 + quad * 8;
  short* op = wfrag + (((size_t)(dir * 64 + T) * 8 + ks) * 64 + lane) * 8;
#pragma unroll
  for (int j = 0; j < 8; ++j) op[j] = (short)f2bf(wp[j]);
}

// ---------------------------------------------------------------------------
// Input projection GEMM (NT), fp32: C[dir][m][n] = sum_k A[m][k]*B[dir][n][k] + bias
__global__ __launch_bounds__(256) void gemm_xg(
    const float* __restrict__ A, int K,
    const float* __restrict__ B, int dirStrideB,
    const float* __restrict__ bias,
    float* __restrict__ C) {
  int dir = blockIdx.z;
  const float* Bp = B + (size_t)dir * dirStrideB;
  const float* bi = bias + (size_t)dir * 2 * G4;
  float* Cp = C + (size_t)dir * ROWS * G4;
  int n0 = blockIdx.x * 64, m0 = blockIdx.y * 64;
  int tid = threadIdx.x;
  int tx = tid & 15, ty = tid >> 4;
  __shared__ float As[16][68];
  __shared__ float Bs[16][68];
  float acc[4][4] = {{0.f}};
  int lm = tid >> 2;
  int lk = (tid & 3) * 4;
  for (int k0 = 0; k0 < K; k0 += 16) {
    float4 av = *(const float4*)&A[(size_t)(m0 + lm) * K + k0 + lk];
    float4 bv = *(const float4*)&Bp[(size_t)(n0 + lm) * K + k0 + lk];
    As[lk + 0][lm] = av.x; As[lk + 1][lm] = av.y;
    As[lk + 2][lm] = av.z; As[lk + 3][lm] = av.w;
    Bs[lk + 0][lm] = bv.x; Bs[lk + 1][lm] = bv.y;
    Bs[lk + 2][lm] = bv.z; Bs[lk + 3][lm] = bv.w;
    __syncthreads();
#pragma unroll
    for (int kk = 0; kk < 16; ++kk) {
      float4 a = *(const float4*)&As[kk][ty * 4];
      float4 b4 = *(const float4*)&Bs[kk][tx * 4];
      acc[0][0] += a.x * b4.x; acc[0][1] += a.x * b4.y;
      acc[0][2] += a.x * b4.z; acc[0][3] += a.x * b4.w;
      acc[1][0] += a.y * b4.x; acc[1][1] += a.y * b4.y;
      acc[1][2] += a.y * b4.z; acc[1][3] += a.y * b4.w;
      acc[2][0] += a.z * b4.x; acc[2][1] += a.z * b4.y;
      acc[2][2] += a.z * b4.z; acc[2][3] += a.z * b4.w;
      acc[3][0] += a.w * b4.x; acc[3][1] += a.w * b4.y;
      acc[3][2] += a.w * b4.z; acc[3][3] += a.w * b4.w;
    }
    __syncthreads();
  }
  int n = n0 + tx * 4;
  float4 b0 = *(const float4*)&bi[n];
  float4 b1 = *(const float4*)&bi[G4 + n];
  float bs0 = b0.x + b1.x, bs1 = b0.y + b1.y, bs2 = b0.z + b1.z, bs3 = b0.w + b1.w;
#pragma unroll
  for (int i = 0; i < 4; ++i) {
    float4 v;
    v.x = acc[i][0] + bs0; v.y = acc[i][1] + bs1;
    v.z = acc[i][2] + bs2; v.w = acc[i][3] + bs3;
    *(float4*)&Cp[(size_t)(m0 + ty * 4 + i) * G4 + n] = v;
  }
}

// ---------------------------------------------------------------------------
// MFMA LSTM recurrence: one block per direction, 1024 threads (16 waves).
// All 16 batches processed together: per step G[16x1024] = xg[t] + H[16x256]Whh^T.
// W_hh held register-resident as bf16 B-fragments (128 VGPR/thread).
// Wave w owns tiles {w, 16+w, 32+w, 48+w} -> gates i,f,g,o for j in [16w,16w+16)
// live in the same lanes -> in-register LSTM cell epilogue, c-state in VGPRs.
#define HPAD 264   // H row stride in bf16 elems (528 B): 2-way-conflict ds_read_b128
__global__ __launch_bounds__(1024) void lstm_mfma(
    const float* __restrict__ xg, const short* __restrict__ wfrag,
    float* __restrict__ out) {
  int dir = blockIdx.x;
  int tid = threadIdx.x;
  int wv = tid >> 6;          // wave 0..15
  int lane = tid & 63;
  int quad = lane >> 4;       // 0..3
  int col = lane & 15;        // 0..15
  int j16 = 16 * wv + col;    // hidden index this lane's epilogue handles

  __shared__ short Hbuf[2][16 * HPAD];

  // zero H(t=0)
  for (int idx = tid; idx < 16 * HPAD; idx += 1024) Hbuf[0][idx] = 0;

  // load weight fragments (once)
  short8 bfrag[4][8];
#pragma unroll
  for (int g = 0; g < 4; ++g)
#pragma unroll
    for (int ks = 0; ks < 8; ++ks)
      bfrag[g][ks] = *(const short8*)(wfrag +
          (((size_t)(dir * 64 + g * 16 + wv) * 8 + ks) * 64 + lane) * 8);

  const float* xgb = xg + (size_t)dir * ROWS * G4;
  // per-lane row base pointers for xg loads / h stores (b = quad*4 + r)
  const float* xrow[4];
  float* orow[4];
#pragma unroll
  for (int r = 0; r < 4; ++r) {
    int b = quad * 4 + r;
    xrow[r] = xgb + (size_t)b * SS * G4 + j16;       // + pos*G4 + g*256 per step
    orow[r] = out + (size_t)b * SS * 512 + dir * HH + j16;  // + pos*512 per step
  }

  float cst[4] = {0.f, 0.f, 0.f, 0.f};
  int cur = 0;
  __syncthreads();

  for (int t = 0; t < SS; ++t) {
    int pos = dir ? (SS - 1 - t) : t;
    // issue xg loads early (consumed only in epilogue)
    float xv[4][4];
#pragma unroll
    for (int r = 0; r < 4; ++r) {
      const float* p = xrow[r] + (size_t)pos * G4;
#pragma unroll
      for (int g = 0; g < 4; ++g) xv[g][r] = p[g * 256];
    }

    f32x4 acc[4];
#pragma unroll
    for (int g = 0; g < 4; ++g) acc[g] = (f32x4){0.f, 0.f, 0.f, 0.f};

    const short* hrow = &Hbuf[cur][0] + col * HPAD + quad * 8;
#pragma unroll
    for (int ks = 0; ks < 8; ++ks) {
      short8 af = *(const short8*)(hrow + ks * 32);
      acc[0] = __builtin_amdgcn_mfma_f32_16x16x32_bf16(af, bfrag[0][ks], acc[0], 0, 0, 0);
      acc[1] = __builtin_amdgcn_mfma_f32_16x16x32_bf16(af, bfrag[1][ks], acc[1], 0, 0, 0);
      acc[2] = __builtin_amdgcn_mfma_f32_16x16x32_bf16(af, bfrag[2][ks], acc[2], 0, 0, 0);
      acc[3] = __builtin_amdgcn_mfma_f32_16x16x32_bf16(af, bfrag[3][ks], acc[3], 0, 0, 0);
    }

    int nxt = cur ^ 1;
#pragma unroll
    for (int r = 0; r < 4; ++r) {
      float ig = acc[0][r] + xv[0][r];
      float fg = acc[1][r] + xv[1][r];
      float gg = acc[2][r] + xv[2][r];
      float og = acc[3][r] + xv[3][r];
      float si = 1.f / (1.f + expf(-ig));
      float sf = 1.f / (1.f + expf(-fg));
      float so = 1.f / (1.f + expf(-og));
      cst[r] = sf * cst[r] + si * tanhf(gg);
      float h = so * tanhf(cst[r]);
      Hbuf[nxt][(quad * 4 + r) * HPAD + j16] = (short)f2bf(h);
      orow[r][(size_t)pos * 512] = h;
    }
    __syncthreads();
    cur = nxt;
  }
}

// ---------------------------------------------------------------------------
// LayerNorm + 9-way linear. One wave per row.
__global__ __launch_bounds__(64) void ln_logits(
    const float* __restrict__ X, const float* __restrict__ g,
    const float* __restrict__ bt, const float* __restrict__ W,
    const float* __restrict__ lb, float* __restrict__ out) {
  int row = blockIdx.x;
  int lane = threadIdx.x;
  const float* x = X + (size_t)row * 512;
  float v[8];
  float s = 0.f, s2 = 0.f;
#pragma unroll
  for (int i = 0; i < 8; ++i) {
    v[i] = x[lane + 64 * i];
    s += v[i];
    s2 += v[i] * v[i];
  }
#pragma unroll
  for (int off = 32; off; off >>= 1) {
    s += __shfl_down(s, off, 64);
    s2 += __shfl_down(s2, off, 64);
  }
  s = __shfl(s, 0, 64);
  s2 = __shfl(s2, 0, 64);
  float mu = s * (1.f / 512.f);
  float var = s2 * (1.f / 512.f) - mu * mu;
  float rstd = rsqrtf(var + 1e-5f);
  float y[8];
#pragma unroll
  for (int i = 0; i < 8; ++i) {
    int e = lane + 64 * i;
    y[i] = (v[i] - mu) * rstd * g[e] + bt[e];
  }
  for (int l = 0; l < LL; ++l) {
    float p = 0.f;
#pragma unroll
    for (int i = 0; i < 8; ++i) p += y[i] * W[(size_t)l * 512 + lane + 64 * i];
#pragma unroll
    for (int off = 32; off; off >>= 1) p += __shfl_down(p, off, 64);
    if (lane == 0) out[(size_t)row * LL + l] = p + lb[l];
  }
}

// ---------------------------------------------------------------------------
// CRF numerator + denominator + loss. One block of 256 threads.
__global__ __launch_bounds__(256) void crf_kernel(
    const float* __restrict__ logits, const int* __restrict__ labels,
    const int* __restrict__ mask, const float* __restrict__ cs,
    const float* __restrict__ ce, const float* __restrict__ ct,
    float* __restrict__ loss_out) {
  __shared__ float trans[9][12];
  __shared__ float alpha[2][BB][12];
  __shared__ float numsh[BB];
  __shared__ float res[BB];
  int tid = threadIdx.x;
  int b = tid >> 4;
  int i = tid & 15;
  if (tid < 81) trans[tid / 9][tid % 9] = ct[tid];
  __syncthreads();
  const float* lg = logits + (size_t)b * SS * LL;
  const int* lbp = labels + (size_t)b * SS;
  const int* mk = mask + (size_t)b * SS;

  float np = 0.f;
  int msum = 0;
  for (int t = i; t < SS; t += 16) {
    msum += mk[t];
    if (t == 0) {
      int l0 = lbp[0];
      np += cs[l0] + lg[l0];
    } else {
      float m = (float)mk[t];
      np += (trans[lbp[t - 1]][lbp[t]] + lg[(size_t)t * LL + lbp[t]]) * m;
    }
  }
#pragma unroll
  for (int off = 8; off; off >>= 1) {
    np += __shfl_down(np, off, 16);
    msum += __shfl_down(msum, off, 16);
  }
  if (i == 0) {
    int last = msum - 1;
    numsh[b] = np + ce[lbp[last]];
  }

  if (i < LL) alpha[0][b][i] = cs[i] + lg[i];
  int cur = 0;
  for (int t = 1; t < SS; ++t) {
    if (i < LL) {
      float e = lg[(size_t)t * LL + i];
      float av[9];
      float mmax = -1e30f;
#pragma unroll
      for (int p = 0; p < LL; ++p) {
        float vv = alpha[cur][b][p] + trans[p][i];
        av[p] = vv;
        mmax = fmaxf(mmax, vv);
      }
      float ssum = 0.f;
#pragma unroll
      for (int p = 0; p < LL; ++p) ssum += expf(av[p] - mmax);
      float anew = e + mmax + logf(ssum);
      float aold = alpha[cur][b][i];
      alpha[cur ^ 1][b][i] = (mk[t] > 0) ? anew : aold;
    }
    cur ^= 1;
  }
  if (i == 0) {
    float arr[9];
    float m2 = -1e30f;
#pragma unroll
    for (int cc = 0; cc < LL; ++cc) {
      arr[cc] = alpha[cur][b][cc] + ce[cc];
      m2 = fmaxf(m2, arr[cc]);
    }
    float ssd = 0.f;
#pragma unroll
    for (int cc = 0; cc < LL; ++cc) ssd += expf(arr[cc] - m2);
    float denom = m2 + logf(ssd);
    res[b] = numsh[b] - denom;
  }
  __syncthreads();
  if (tid == 0) {
    float Lsum = 0.f;
    for (int b2 = 0; b2 < BB; ++b2) Lsum += res[b2];
    loss_out[0] = -Lsum;
  }
}

// ---------------------------------------------------------------------------
extern "C" void kernel_launch(void* const* d_in, const int* in_sizes, int n_in,
                              void* d_out, int out_size, void* d_ws, size_t ws_size,
                              hipStream_t stream) {
  const int* input_ids = (const int*)d_in[0];
  const int* attn_mask = (const int*)d_in[1];
  const int* labels = (const int*)d_in[2];
  const float* embedding = (const float*)d_in[3];
  const float* w_ih_l0 = (const float*)d_in[4];
  const float* w_ih_rest = (const float*)d_in[5];
  const float* w_hh = (const float*)d_in[6];
  const float* bvec = (const float*)d_in[7];
  const float* ln_g = (const float*)d_in[8];
  const float* ln_b = (const float*)d_in[9];
  const float* lin_w = (const float*)d_in[10];
  const float* lin_b = (const float*)d_in[11];
  const float* crf_start = (const float*)d_in[12];
  const float* crf_end = (const float*)d_in[13];
  const float* crf_trans = (const float*)d_in[14];
  float* out = (float*)d_out;
  float* ws = (float*)d_ws;

  float* xA = ws;                          // 4096*512 f32
  float* xB = xA + (size_t)ROWS * 512;     // 4096*512 f32
  float* xg = xB + (size_t)ROWS * 512;     // 2*4096*1024 f32
  short* wfrag = (short*)(xg + (size_t)2 * ROWS * G4);  // 2*64*8*64*8 bf16 = 1 MB

  embed_kernel<<<ROWS, 256, 0, stream>>>(input_ids, embedding, xA);

  float* cur = xA;
  float* nxt = xB;
  for (int l = 0; l < 4; ++l) {
    int K = l ? 512 : 256;
    const float* wih = l ? (w_ih_rest + (size_t)(l - 1) * 2 * G4 * 512) : w_ih_l0;
    pack_whh<<<dim3(64, 8, 2), 64, 0, stream>>>(
        w_hh + (size_t)l * 2 * G4 * HH, wfrag);
    gemm_xg<<<dim3(16, 64, 2), 256, 0, stream>>>(
        cur, K, wih, G4 * K, bvec + (size_t)l * 2 * 2 * G4, xg);
    lstm_mfma<<<2, 1024, 0, stream>>>(xg, wfrag, nxt);
    float* tmp = cur; cur = nxt; nxt = tmp;
  }

  ln_logits<<<ROWS, 64, 0, stream>>>(cur, ln_g, ln_b, lin_w, lin_b, out);
  crf_kernel<<<1, 256, 0, stream>>>(out, labels, attn_mask, crf_start, crf_end,
                                    crf_trans, out + (size_t)ROWS * LL);
}

// Round 3
// 4663.413 us; speedup vs baseline: 2.2467x; 2.0500x over previous
//
#include <hip/hip_runtime.h>
#include <math.h>

// Problem constants: B=16, S=256, E=256, H=256, V=50000, L=9
#define BB 16
#define SS 256
#define LL 9
#define ROWS 4096
#define HPITCH 288     // bytes per H row in LDS (fp8), 288 = 9*32 -> balanced banks
#define APITCH 40      // bf16 elems per LDS row in GEMM (80 B, 16B-aligned, conflict-free)

typedef __attribute__((ext_vector_type(8))) short short8;   // 8 bf16
typedef __attribute__((ext_vector_type(4))) float f32x4;    // MFMA acc

#define WSCALE 1024.0f
#define HSCALE 256.0f
#define KINV   (1.0f / (WSCALE * HSCALE))

__device__ __forceinline__ unsigned short f2bf(float f) {
  unsigned u = __float_as_uint(f);
  return (unsigned short)((u + 0x7FFF + ((u >> 16) & 1)) >> 16);  // RNE
}
__device__ __forceinline__ float bf2f(unsigned short s) {
  return __uint_as_float(((unsigned)s) << 16);
}
__device__ __forceinline__ float tanh_fast(float x) {
  float a = fabsf(x);
  float e = __expf(-2.0f * a);
  float t = (1.0f - e) / (1.0f + e);
  return x < 0.0f ? -t : t;
}
__device__ __forceinline__ float sigmoid_fast(float x) {
  return 1.0f / (1.0f + __expf(-x));
}

// ---------------------------------------------------------------------------
// Embedding gather -> bf16 x0 [4096][256]
__global__ __launch_bounds__(256) void embed_bf16(
    const int* __restrict__ ids, const float* __restrict__ emb,
    unsigned short* __restrict__ x0) {
  int row = blockIdx.x;
  int id = ids[row];
  x0[(size_t)row * 256 + threadIdx.x] = f2bf(emb[(size_t)id * 256 + threadIdx.x]);
}

// ---------------------------------------------------------------------------
// Pack w_hh (one layer) into fp8 e4m3 MFMA B-fragments, scaled by WSCALE.
// wfrag[dir][nb(64)][ks(8)][lane(64)] : 8 bytes = w[dir][n=nb*16+col][k=ks*32+quad*8+j]
__global__ __launch_bounds__(64) void pack_whh_fp8(
    const float* __restrict__ w, unsigned long long* __restrict__ wfrag) {
  int nb = blockIdx.x, ks = blockIdx.y, dir = blockIdx.z;
  int lane = threadIdx.x, quad = lane >> 4, col = lane & 15;
  const float* wp = w + (size_t)dir * 1024 * 256 + (size_t)(nb * 16 + col) * 256 +
                    ks * 32 + quad * 8;
  float v[8];
#pragma unroll
  for (int j = 0; j < 8; ++j) v[j] = wp[j] * WSCALE;
  unsigned lo = __builtin_amdgcn_cvt_pk_fp8_f32(v[0], v[1], 0, false);
  lo = __builtin_amdgcn_cvt_pk_fp8_f32(v[2], v[3], lo, true);
  unsigned hi = __builtin_amdgcn_cvt_pk_fp8_f32(v[4], v[5], 0, false);
  hi = __builtin_amdgcn_cvt_pk_fp8_f32(v[6], v[7], hi, true);
  wfrag[((size_t)(dir * 64 + nb) * 8 + ks) * 64 + lane] =
      (unsigned long long)lo | ((unsigned long long)hi << 32);
}

// ---------------------------------------------------------------------------
// biasP[dir][n'] = b_ih[n] + b_hh[n],  n' = j*4+g, n = g*256+j
__global__ __launch_bounds__(256) void bias_perm(
    const float* __restrict__ b2, float* __restrict__ biasP) {
  int i = blockIdx.x * 256 + threadIdx.x;  // 0..2047
  int dir = i >> 10, np = i & 1023;
  int n = ((np & 3) << 8) + (np >> 2);
  biasP[i] = b2[dir * 2048 + n] + b2[dir * 2048 + 1024 + n];
}

// ---------------------------------------------------------------------------
// bf16 MFMA GEMM: xgP[dir][row][n'] = sum_k A[row][k]*Wih[dir][n(n')][k] + biasP
// A bf16 [4096][K], Wih fp32, output bf16 in gate-interleaved layout n'=j*4+g.
// Block 256 thr (4 waves), tile M64 x N64, BK=32.
__global__ __launch_bounds__(256) void gemm_xg_bf16(
    const unsigned short* __restrict__ A, int K,
    const float* __restrict__ Wih,
    const float* __restrict__ biasP,
    unsigned short* __restrict__ xgP) {
  int dir = blockIdx.z;
  const float* Bw = Wih + (size_t)dir * 1024 * K;
  int n0 = blockIdx.x * 64, m0 = blockIdx.y * 64;
  int tid = threadIdx.x;
  int wv = tid >> 6, lane = tid & 63, quad = lane >> 4, col = lane & 15;
  __shared__ unsigned short As[64 * APITCH];
  __shared__ unsigned short Bs[64 * APITCH];
  int lr = tid >> 2;           // 0..63
  int lk = (tid & 3) * 8;      // 0,8,16,24
  int nprime = n0 + lr;
  int nphys = ((nprime & 3) << 8) + (nprime >> 2);
  f32x4 acc[4];
#pragma unroll
  for (int nt = 0; nt < 4; ++nt) acc[nt] = (f32x4){0.f, 0.f, 0.f, 0.f};

  for (int k0 = 0; k0 < K; k0 += 32) {
    short8 av = *(const short8*)&A[(size_t)(m0 + lr) * K + k0 + lk];
    float4 b0 = *(const float4*)&Bw[(size_t)nphys * K + k0 + lk];
    float4 b1 = *(const float4*)&Bw[(size_t)nphys * K + k0 + lk + 4];
    short8 bv;
    bv[0] = (short)f2bf(b0.x); bv[1] = (short)f2bf(b0.y);
    bv[2] = (short)f2bf(b0.z); bv[3] = (short)f2bf(b0.w);
    bv[4] = (short)f2bf(b1.x); bv[5] = (short)f2bf(b1.y);
    bv[6] = (short)f2bf(b1.z); bv[7] = (short)f2bf(b1.w);
    __syncthreads();   // previous iteration's fragment reads complete
    *(short8*)&As[lr * APITCH + lk] = av;
    *(short8*)&Bs[lr * APITCH + lk] = bv;
    __syncthreads();
    short8 af = *(const short8*)&As[(wv * 16 + col) * APITCH + quad * 8];
#pragma unroll
    for (int nt = 0; nt < 4; ++nt) {
      short8 bf = *(const short8*)&Bs[(nt * 16 + col) * APITCH + quad * 8];
      acc[nt] = __builtin_amdgcn_mfma_f32_16x16x32_bf16(af, bf, acc[nt], 0, 0, 0);
    }
  }
#pragma unroll
  for (int nt = 0; nt < 4; ++nt) {
    int np = n0 + nt * 16 + col;
    float bia = biasP[dir * 1024 + np];
#pragma unroll
    for (int r = 0; r < 4; ++r) {
      int row = m0 + wv * 16 + quad * 4 + r;
      xgP[((size_t)dir * ROWS + row) * 1024 + np] = f2bf(acc[nt][r] + bia);
    }
  }
}

// ---------------------------------------------------------------------------
// fp8 MFMA LSTM recurrence: one block per direction, 512 threads (8 waves).
// W_hh register-resident as fp8 B-fragments (128 VGPR). H fp8 in LDS.
// Wave w owns hidden blocks {2w, 2w+1} x 4 gates = 8 N-tiles; epilogue in-register.
__global__ __launch_bounds__(512, 2) void lstm_fp8(
    const unsigned short* __restrict__ xgP,   // [2][4096][1024] bf16 n'=j*4+g
    const long* __restrict__ wfrag,           // [2][64][8][64] i64
    unsigned short* __restrict__ xout) {      // [4096][512] bf16
  int dir = blockIdx.x;
  int tid = threadIdx.x;
  int wv = tid >> 6, lane = tid & 63;
  int quad = lane >> 4, col = lane & 15;

  __shared__ __align__(16) unsigned char Hbuf[2][16 * HPITCH];

  int* hz = (int*)&Hbuf[0][0];
  for (int i = tid; i < 16 * HPITCH / 4; i += 512) hz[i] = 0;

  // load weight fragments once: wf[hbi][g][ks]
  long wf[2][4][8];
#pragma unroll
  for (int hbi = 0; hbi < 2; ++hbi)
#pragma unroll
    for (int g = 0; g < 4; ++g) {
      int nb = g * 16 + 2 * wv + hbi;
      const long* p = wfrag + ((size_t)(dir * 64 + nb) * 8) * 64 + lane;
#pragma unroll
      for (int ks = 0; ks < 8; ++ks) wf[hbi][g][ks] = p[(size_t)ks * 64];
    }

  const unsigned short* xb = xgP + (size_t)dir * ROWS * 1024;
  float cst[2][4] = {{0.f, 0.f, 0.f, 0.f}, {0.f, 0.f, 0.f, 0.f}};
  int cur = 0;
  __syncthreads();

  for (int t = 0; t < SS; ++t) {
    int pos = dir ? (SS - 1 - t) : t;
    // prefetch xg (independent of h -> overlaps MFMA)
    ushort4 xq[2][4];
#pragma unroll
    for (int hbi = 0; hbi < 2; ++hbi) {
      int j = 16 * (2 * wv + hbi) + col;
#pragma unroll
      for (int r = 0; r < 4; ++r) {
        int b = quad * 4 + r;
        xq[hbi][r] = *(const ushort4*)&xb[((size_t)(b * SS + pos)) * 1024 + j * 4];
      }
    }

    f32x4 acc[2][4];
#pragma unroll
    for (int hbi = 0; hbi < 2; ++hbi)
#pragma unroll
      for (int g = 0; g < 4; ++g) acc[hbi][g] = (f32x4){0.f, 0.f, 0.f, 0.f};

    const unsigned char* hrow = &Hbuf[cur][col * HPITCH + quad * 8];
#pragma unroll
    for (int ks = 0; ks < 8; ++ks) {
      long af = *(const long*)(hrow + ks * 32);
#pragma unroll
      for (int hbi = 0; hbi < 2; ++hbi) {
        acc[hbi][0] = __builtin_amdgcn_mfma_f32_16x16x32_fp8_fp8(af, wf[hbi][0][ks], acc[hbi][0], 0, 0, 0);
        acc[hbi][1] = __builtin_amdgcn_mfma_f32_16x16x32_fp8_fp8(af, wf[hbi][1][ks], acc[hbi][1], 0, 0, 0);
        acc[hbi][2] = __builtin_amdgcn_mfma_f32_16x16x32_fp8_fp8(af, wf[hbi][2][ks], acc[hbi][2], 0, 0, 0);
        acc[hbi][3] = __builtin_amdgcn_mfma_f32_16x16x32_fp8_fp8(af, wf[hbi][3][ks], acc[hbi][3], 0, 0, 0);
      }
    }

    int nxt = cur ^ 1;
#pragma unroll
    for (int hbi = 0; hbi < 2; ++hbi) {
      int j = 16 * (2 * wv + hbi) + col;
#pragma unroll
      for (int r = 0; r < 4; ++r) {
        int b = quad * 4 + r;
        float gi = acc[hbi][0][r] * KINV + bf2f(xq[hbi][r].x);
        float gf = acc[hbi][1][r] * KINV + bf2f(xq[hbi][r].y);
        float gg = acc[hbi][2][r] * KINV + bf2f(xq[hbi][r].z);
        float go = acc[hbi][3][r] * KINV + bf2f(xq[hbi][r].w);
        float si = sigmoid_fast(gi);
        float sf = sigmoid_fast(gf);
        float so = sigmoid_fast(go);
        float c = sf * cst[hbi][r] + si * tanh_fast(gg);
        cst[hbi][r] = c;
        float h = so * tanh_fast(c);
        unsigned pk = __builtin_amdgcn_cvt_pk_fp8_f32(h * HSCALE, h * HSCALE, 0, false);
        Hbuf[nxt][b * HPITCH + j] = (unsigned char)(pk & 0xFF);
        xout[(size_t)(b * SS + pos) * 512 + dir * 256 + j] = f2bf(h);
      }
    }
    __syncthreads();
    cur = nxt;
  }
}

// ---------------------------------------------------------------------------
// LayerNorm + 9-way linear. One wave per row. X is bf16 [4096][512].
__global__ __launch_bounds__(64) void ln_logits(
    const unsigned short* __restrict__ X, const float* __restrict__ g,
    const float* __restrict__ bt, const float* __restrict__ W,
    const float* __restrict__ lb, float* __restrict__ out) {
  int row = blockIdx.x;
  int lane = threadIdx.x;
  const unsigned short* x = X + (size_t)row * 512;
  float v[8];
  float s = 0.f, s2 = 0.f;
#pragma unroll
  for (int i = 0; i < 8; ++i) {
    v[i] = bf2f(x[lane + 64 * i]);
    s += v[i];
    s2 += v[i] * v[i];
  }
#pragma unroll
  for (int off = 32; off; off >>= 1) {
    s += __shfl_down(s, off, 64);
    s2 += __shfl_down(s2, off, 64);
  }
  s = __shfl(s, 0, 64);
  s2 = __shfl(s2, 0, 64);
  float mu = s * (1.f / 512.f);
  float var = s2 * (1.f / 512.f) - mu * mu;
  float rstd = rsqrtf(var + 1e-5f);
  float y[8];
#pragma unroll
  for (int i = 0; i < 8; ++i) {
    int e = lane + 64 * i;
    y[i] = (v[i] - mu) * rstd * g[e] + bt[e];
  }
  for (int l = 0; l < LL; ++l) {
    float p = 0.f;
#pragma unroll
    for (int i = 0; i < 8; ++i) p += y[i] * W[(size_t)l * 512 + lane + 64 * i];
#pragma unroll
    for (int off = 32; off; off >>= 1) p += __shfl_down(p, off, 64);
    if (lane == 0) out[(size_t)row * LL + l] = p + lb[l];
  }
}

// ---------------------------------------------------------------------------
// CRF numerator + denominator + loss. One block of 256 threads.
__global__ __launch_bounds__(256) void crf_kernel(
    const float* __restrict__ logits, const int* __restrict__ labels,
    const int* __restrict__ mask, const float* __restrict__ cs,
    const float* __restrict__ ce, const float* __restrict__ ct,
    float* __restrict__ loss_out) {
  __shared__ float trans[9][12];
  __shared__ float alpha[2][BB][12];
  __shared__ float numsh[BB];
  __shared__ float res[BB];
  int tid = threadIdx.x;
  int b = tid >> 4;
  int i = tid & 15;
  if (tid < 81) trans[tid / 9][tid % 9] = ct[tid];
  __syncthreads();
  const float* lg = logits + (size_t)b * SS * LL;
  const int* lbp = labels + (size_t)b * SS;
  const int* mk = mask + (size_t)b * SS;

  float np = 0.f;
  int msum = 0;
  for (int t = i; t < SS; t += 16) {
    msum += mk[t];
    if (t == 0) {
      int l0 = lbp[0];
      np += cs[l0] + lg[l0];
    } else {
      float m = (float)mk[t];
      np += (trans[lbp[t - 1]][lbp[t]] + lg[(size_t)t * LL + lbp[t]]) * m;
    }
  }
#pragma unroll
  for (int off = 8; off; off >>= 1) {
    np += __shfl_down(np, off, 16);
    msum += __shfl_down(msum, off, 16);
  }
  if (i == 0) {
    int last = msum - 1;
    numsh[b] = np + ce[lbp[last]];
  }

  if (i < LL) alpha[0][b][i] = cs[i] + lg[i];
  int cur = 0;
  for (int t = 1; t < SS; ++t) {
    if (i < LL) {
      float e = lg[(size_t)t * LL + i];
      float av[9];
      float mmax = -1e30f;
#pragma unroll
      for (int p = 0; p < LL; ++p) {
        float vv = alpha[cur][b][p] + trans[p][i];
        av[p] = vv;
        mmax = fmaxf(mmax, vv);
      }
      float ssum = 0.f;
#pragma unroll
      for (int p = 0; p < LL; ++p) ssum += __expf(av[p] - mmax);
      float anew = e + mmax + logf(ssum);
      float aold = alpha[cur][b][i];
      alpha[cur ^ 1][b][i] = (mk[t] > 0) ? anew : aold;
    }
    cur ^= 1;
  }
  if (i == 0) {
    float arr[9];
    float m2 = -1e30f;
#pragma unroll
    for (int cc = 0; cc < LL; ++cc) {
      arr[cc] = alpha[cur][b][cc] + ce[cc];
      m2 = fmaxf(m2, arr[cc]);
    }
    float ssd = 0.f;
#pragma unroll
    for (int cc = 0; cc < LL; ++cc) ssd += __expf(arr[cc] - m2);
    float denom = m2 + logf(ssd);
    res[b] = numsh[b] - denom;
  }
  __syncthreads();
  if (tid == 0) {
    float Lsum = 0.f;
    for (int b2 = 0; b2 < BB; ++b2) Lsum += res[b2];
    loss_out[0] = -Lsum;
  }
}

// ---------------------------------------------------------------------------
extern "C" void kernel_launch(void* const* d_in, const int* in_sizes, int n_in,
                              void* d_out, int out_size, void* d_ws, size_t ws_size,
                              hipStream_t stream) {
  const int* input_ids = (const int*)d_in[0];
  const int* attn_mask = (const int*)d_in[1];
  const int* labels = (const int*)d_in[2];
  const float* embedding = (const float*)d_in[3];
  const float* w_ih_l0 = (const float*)d_in[4];
  const float* w_ih_rest = (const float*)d_in[5];
  const float* w_hh = (const float*)d_in[6];
  const float* bvec = (const float*)d_in[7];
  const float* ln_g = (const float*)d_in[8];
  const float* ln_b = (const float*)d_in[9];
  const float* lin_w = (const float*)d_in[10];
  const float* lin_b = (const float*)d_in[11];
  const float* crf_start = (const float*)d_in[12];
  const float* crf_end = (const float*)d_in[13];
  const float* crf_trans = (const float*)d_in[14];
  float* out = (float*)d_out;
  char* base = (char*)d_ws;

  unsigned short* x0    = (unsigned short*)(base);                        // 2 MB
  unsigned short* xoutA = (unsigned short*)(base + (2u << 20));           // 4 MB
  unsigned short* xoutB = (unsigned short*)(base + (6u << 20));           // 4 MB
  unsigned short* xgP   = (unsigned short*)(base + (10u << 20));          // 16 MB
  long*           wfrag = (long*)(base + (26u << 20));                    // 512 KB
  float*          biasP = (float*)(base + (26u << 20) + (512u << 10));    // 8 KB

  embed_bf16<<<ROWS, 256, 0, stream>>>(input_ids, embedding, x0);

  const unsigned short* cur = x0;
  unsigned short* nxt = xoutA;
  for (int l = 0; l < 4; ++l) {
    int K = l ? 512 : 256;
    const float* wih = l ? (w_ih_rest + (size_t)(l - 1) * 2 * 1024 * 512) : w_ih_l0;
    pack_whh_fp8<<<dim3(64, 8, 2), 64, 0, stream>>>(
        w_hh + (size_t)l * 2 * 1024 * 256, (unsigned long long*)wfrag);
    bias_perm<<<8, 256, 0, stream>>>(bvec + (size_t)l * 4096, biasP);
    gemm_xg_bf16<<<dim3(16, 64, 2), 256, 0, stream>>>(cur, K, wih, biasP, xgP);
    lstm_fp8<<<2, 512, 0, stream>>>(xgP, wfrag, nxt);
    cur = nxt;
    nxt = (nxt == xoutA) ? xoutB : xoutA;
  }

  ln_logits<<<ROWS, 64, 0, stream>>>(cur, ln_g, ln_b, lin_w, lin_b, out);
  crf_kernel<<<1, 256, 0, stream>>>(out, labels, attn_mask, crf_start, crf_end,
                                    crf_trans, out + (size_t)ROWS * LL);
}

// Round 4
// 2151.156 us; speedup vs baseline: 4.8706x; 2.1679x over previous
//
#include <hip/hip_runtime.h>
#include <math.h>

// Problem constants: B=16, S=256, E=256, H=256, V=50000, L=9
#define BB 16
#define SS 256
#define LL 9
#define ROWS 4096
#define HPITCH 288     // bytes per H row in LDS (fp8)
#define APITCH 40      // bf16 elems per LDS row in GEMM (80 B)

typedef __attribute__((ext_vector_type(8))) short short8;   // 8 bf16
typedef __attribute__((ext_vector_type(4))) float f32x4;    // MFMA acc

#define WSCALE 1024.0f
#define HSCALE 256.0f
#define KINV   (1.0f / (WSCALE * HSCALE))
#define LOG2E  1.44269504f

__device__ __forceinline__ unsigned short f2bf(float f) {
  unsigned u = __float_as_uint(f);
  return (unsigned short)((u + 0x7FFF + ((u >> 16) & 1)) >> 16);  // RNE
}
__device__ __forceinline__ float bf2f(unsigned short s) {
  return __uint_as_float(((unsigned)s) << 16);
}
// division-free fast sigmoid/tanh (v_exp + v_rcp, no fp32-div sequence)
__device__ __forceinline__ float sigmoid_fast(float x) {
  return __builtin_amdgcn_rcpf(1.0f + __builtin_amdgcn_exp2f(-LOG2E * x));
}
__device__ __forceinline__ float tanh_fast(float x) {
  float a = fabsf(x);
  float e = __builtin_amdgcn_exp2f(-2.0f * LOG2E * a);
  float r = (1.0f - e) * __builtin_amdgcn_rcpf(1.0f + e);
  return __builtin_copysignf(r, x);
}

// ---------------------------------------------------------------------------
// Embedding gather -> bf16 x0 [4096][256]
__global__ __launch_bounds__(256) void embed_bf16(
    const int* __restrict__ ids, const float* __restrict__ emb,
    unsigned short* __restrict__ x0) {
  int row = blockIdx.x;
  int id = ids[row];
  x0[(size_t)row * 256 + threadIdx.x] = f2bf(emb[(size_t)id * 256 + threadIdx.x]);
}

// ---------------------------------------------------------------------------
// Pack w_hh (one layer) into fp8 e4m3 MFMA B-fragments, scaled by WSCALE.
__global__ __launch_bounds__(64) void pack_whh_fp8(
    const float* __restrict__ w, unsigned long long* __restrict__ wfrag) {
  int nb = blockIdx.x, ks = blockIdx.y, dir = blockIdx.z;
  int lane = threadIdx.x, quad = lane >> 4, col = lane & 15;
  const float* wp = w + (size_t)dir * 1024 * 256 + (size_t)(nb * 16 + col) * 256 +
                    ks * 32 + quad * 8;
  float v[8];
#pragma unroll
  for (int j = 0; j < 8; ++j) v[j] = wp[j] * WSCALE;
  unsigned lo = __builtin_amdgcn_cvt_pk_fp8_f32(v[0], v[1], 0, false);
  lo = __builtin_amdgcn_cvt_pk_fp8_f32(v[2], v[3], lo, true);
  unsigned hi = __builtin_amdgcn_cvt_pk_fp8_f32(v[4], v[5], 0, false);
  hi = __builtin_amdgcn_cvt_pk_fp8_f32(v[6], v[7], hi, true);
  wfrag[((size_t)(dir * 64 + nb) * 8 + ks) * 64 + lane] =
      (unsigned long long)lo | ((unsigned long long)hi << 32);
}

// ---------------------------------------------------------------------------
// biasP[dir][n'] = b_ih[n] + b_hh[n],  n' = j*4+g, n = g*256+j
__global__ __launch_bounds__(256) void bias_perm(
    const float* __restrict__ b2, float* __restrict__ biasP) {
  int i = blockIdx.x * 256 + threadIdx.x;  // 0..2047
  int dir = i >> 10, np = i & 1023;
  int n = ((np & 3) << 8) + (np >> 2);
  biasP[i] = b2[dir * 2048 + n] + b2[dir * 2048 + 1024 + n];
}

// ---------------------------------------------------------------------------
// bf16 MFMA GEMM: xgP[dir][row][n'] = sum_k A[row][k]*Wih[dir][n(n')][k] + biasP
__global__ __launch_bounds__(256) void gemm_xg_bf16(
    const unsigned short* __restrict__ A, int K,
    const float* __restrict__ Wih,
    const float* __restrict__ biasP,
    unsigned short* __restrict__ xgP) {
  int dir = blockIdx.z;
  const float* Bw = Wih + (size_t)dir * 1024 * K;
  int n0 = blockIdx.x * 64, m0 = blockIdx.y * 64;
  int tid = threadIdx.x;
  int wv = tid >> 6, lane = tid & 63, quad = lane >> 4, col = lane & 15;
  __shared__ unsigned short As[64 * APITCH];
  __shared__ unsigned short Bs[64 * APITCH];
  int lr = tid >> 2;
  int lk = (tid & 3) * 8;
  int nprime = n0 + lr;
  int nphys = ((nprime & 3) << 8) + (nprime >> 2);
  f32x4 acc[4];
#pragma unroll
  for (int nt = 0; nt < 4; ++nt) acc[nt] = (f32x4){0.f, 0.f, 0.f, 0.f};

  for (int k0 = 0; k0 < K; k0 += 32) {
    short8 av = *(const short8*)&A[(size_t)(m0 + lr) * K + k0 + lk];
    float4 b0 = *(const float4*)&Bw[(size_t)nphys * K + k0 + lk];
    float4 b1 = *(const float4*)&Bw[(size_t)nphys * K + k0 + lk + 4];
    short8 bv;
    bv[0] = (short)f2bf(b0.x); bv[1] = (short)f2bf(b0.y);
    bv[2] = (short)f2bf(b0.z); bv[3] = (short)f2bf(b0.w);
    bv[4] = (short)f2bf(b1.x); bv[5] = (short)f2bf(b1.y);
    bv[6] = (short)f2bf(b1.z); bv[7] = (short)f2bf(b1.w);
    __syncthreads();
    *(short8*)&As[lr * APITCH + lk] = av;
    *(short8*)&Bs[lr * APITCH + lk] = bv;
    __syncthreads();
    short8 af = *(const short8*)&As[(wv * 16 + col) * APITCH + quad * 8];
#pragma unroll
    for (int nt = 0; nt < 4; ++nt) {
      short8 bf = *(const short8*)&Bs[(nt * 16 + col) * APITCH + quad * 8];
      acc[nt] = __builtin_amdgcn_mfma_f32_16x16x32_bf16(af, bf, acc[nt], 0, 0, 0);
    }
  }
#pragma unroll
  for (int nt = 0; nt < 4; ++nt) {
    int np = n0 + nt * 16 + col;
    float bia = biasP[dir * 1024 + np];
#pragma unroll
    for (int r = 0; r < 4; ++r) {
      int row = m0 + wv * 16 + quad * 4 + r;
      xgP[((size_t)dir * ROWS + row) * 1024 + np] = f2bf(acc[nt][r] + bia);
    }
  }
}

// ---------------------------------------------------------------------------
// fp8 MFMA LSTM recurrence, batch-split: grid = 8 blocks (bg*2+dir), M=4 batches
// per block, 512 threads (8 waves, 2/SIMD). W_hh register-resident fp8 B-frags.
// Per step: MFMA (all waves) -> raw gates to LDS (quad0 lanes, b128) -> barrier
// -> epilogue 2 cells/thread (division-free) -> H fp8 to LDS -> barrier.
__global__ __launch_bounds__(512, 2) void lstm_fp8(
    const unsigned short* __restrict__ xgP,   // [2][4096][1024] bf16 n'=j*4+g
    const long* __restrict__ wfrag,           // [2][64][8][64] i64
    unsigned short* __restrict__ xout) {      // [4096][512] bf16
  int dir = blockIdx.x & 1;
  int bg = blockIdx.x >> 1;            // batch group: batches bg*4 .. bg*4+3
  int tid = threadIdx.x;
  int wv = tid >> 6, lane = tid & 63;
  int quad = lane >> 4, col = lane & 15;

  __shared__ __align__(16) unsigned char Hbuf[2][16 * HPITCH];
  __shared__ __align__(16) float gbuf[4 * 256 * 4];   // [b][j][g]

  // zero BOTH H buffers (rows 4..15 stay zero forever)
  int* hz = (int*)&Hbuf[0][0];
  for (int i = tid; i < 2 * 16 * HPITCH / 4; i += 512) hz[i] = 0;

  // weight fragments, loaded once: wf[hbi][g][ks]
  long wf[2][4][8];
#pragma unroll
  for (int hbi = 0; hbi < 2; ++hbi)
#pragma unroll
    for (int g = 0; g < 4; ++g) {
      int nb = g * 16 + 2 * wv + hbi;
      const long* p = wfrag + ((size_t)(dir * 64 + nb) * 8) * 64 + lane;
#pragma unroll
      for (int ks = 0; ks < 8; ++ks) wf[hbi][g][ks] = p[(size_t)ks * 64];
    }

  // epilogue cell mapping (fixed across t): 2 cells per thread
  int eb = tid >> 7;                 // local batch 0..3
  int j0 = (tid & 127) * 2;          // hidden j, even
  const unsigned short* xb = xgP + ((size_t)dir * ROWS + (size_t)(bg * 4) * SS) * 1024;
  const unsigned short* xq_base = xb + (size_t)eb * SS * 1024 + j0 * 4;
  unsigned short* xo_base = xout + (size_t)(bg * 4 + eb) * SS * 512 + dir * 256 + j0;

  float cst[2] = {0.f, 0.f};
  int cur = 0;
  __syncthreads();

  for (int t = 0; t < SS; ++t) {
    int pos = dir ? (SS - 1 - t) : t;
    // prefetch xg for this thread's 2 cells (8 consecutive bf16 = 16 B)
    short8 xq = *(const short8*)(xq_base + (size_t)pos * 1024);

    // ---- MFMA phase
    f32x4 acc[2][4];
#pragma unroll
    for (int hbi = 0; hbi < 2; ++hbi)
#pragma unroll
      for (int g = 0; g < 4; ++g) acc[hbi][g] = (f32x4){0.f, 0.f, 0.f, 0.f};

    const unsigned char* hrow = &Hbuf[cur][col * HPITCH + quad * 8];
#pragma unroll
    for (int ks = 0; ks < 8; ++ks) {
      long af = *(const long*)(hrow + ks * 32);
#pragma unroll
      for (int hbi = 0; hbi < 2; ++hbi) {
        acc[hbi][0] = __builtin_amdgcn_mfma_f32_16x16x32_fp8_fp8(af, wf[hbi][0][ks], acc[hbi][0], 0, 0, 0);
        acc[hbi][1] = __builtin_amdgcn_mfma_f32_16x16x32_fp8_fp8(af, wf[hbi][1][ks], acc[hbi][1], 0, 0, 0);
        acc[hbi][2] = __builtin_amdgcn_mfma_f32_16x16x32_fp8_fp8(af, wf[hbi][2][ks], acc[hbi][2], 0, 0, 0);
        acc[hbi][3] = __builtin_amdgcn_mfma_f32_16x16x32_fp8_fp8(af, wf[hbi][3][ks], acc[hbi][3], 0, 0, 0);
      }
    }

    // ---- raw gates -> LDS (only quad 0 holds valid batch rows 0..3)
    if (quad == 0) {
#pragma unroll
      for (int hbi = 0; hbi < 2; ++hbi) {
        int j = 16 * (2 * wv + hbi) + col;
#pragma unroll
        for (int r = 0; r < 4; ++r) {
          float4 v = make_float4(acc[hbi][0][r], acc[hbi][1][r],
                                 acc[hbi][2][r], acc[hbi][3][r]);
          *(float4*)&gbuf[(r * 256 + j) * 4] = v;
        }
      }
    }
    __syncthreads();

    // ---- epilogue: 2 cells per thread
    int nxt = cur ^ 1;
    float h01[2];
#pragma unroll
    for (int cc = 0; cc < 2; ++cc) {
      int j = j0 + cc;
      float4 gv = *(const float4*)&gbuf[(eb * 256 + j) * 4];
      float gi = gv.x * KINV + bf2f((unsigned short)xq[cc * 4 + 0]);
      float gf = gv.y * KINV + bf2f((unsigned short)xq[cc * 4 + 1]);
      float gg = gv.z * KINV + bf2f((unsigned short)xq[cc * 4 + 2]);
      float go = gv.w * KINV + bf2f((unsigned short)xq[cc * 4 + 3]);
      float c = sigmoid_fast(gf) * cst[cc] + sigmoid_fast(gi) * tanh_fast(gg);
      cst[cc] = c;
      h01[cc] = sigmoid_fast(go) * tanh_fast(c);
    }
    // H (fp8, 2 adjacent bytes) and xout (2 adjacent bf16)
    unsigned pk = __builtin_amdgcn_cvt_pk_fp8_f32(h01[0] * HSCALE, h01[1] * HSCALE, 0, false);
    *(unsigned short*)&Hbuf[nxt][eb * HPITCH + j0] = (unsigned short)(pk & 0xFFFF);
    unsigned ob = (unsigned)f2bf(h01[0]) | ((unsigned)f2bf(h01[1]) << 16);
    *(unsigned*)(xo_base + (size_t)pos * 512) = ob;
    __syncthreads();
    cur = nxt;
  }
}

// ---------------------------------------------------------------------------
// LayerNorm + 9-way linear. One wave per row. X is bf16 [4096][512].
__global__ __launch_bounds__(64) void ln_logits(
    const unsigned short* __restrict__ X, const float* __restrict__ g,
    const float* __restrict__ bt, const float* __restrict__ W,
    const float* __restrict__ lb, float* __restrict__ out) {
  int row = blockIdx.x;
  int lane = threadIdx.x;
  const unsigned short* x = X + (size_t)row * 512;
  float v[8];
  float s = 0.f, s2 = 0.f;
#pragma unroll
  for (int i = 0; i < 8; ++i) {
    v[i] = bf2f(x[lane + 64 * i]);
    s += v[i];
    s2 += v[i] * v[i];
  }
#pragma unroll
  for (int off = 32; off; off >>= 1) {
    s += __shfl_down(s, off, 64);
    s2 += __shfl_down(s2, off, 64);
  }
  s = __shfl(s, 0, 64);
  s2 = __shfl(s2, 0, 64);
  float mu = s * (1.f / 512.f);
  float var = s2 * (1.f / 512.f) - mu * mu;
  float rstd = rsqrtf(var + 1e-5f);
  float y[8];
#pragma unroll
  for (int i = 0; i < 8; ++i) {
    int e = lane + 64 * i;
    y[i] = (v[i] - mu) * rstd * g[e] + bt[e];
  }
  for (int l = 0; l < LL; ++l) {
    float p = 0.f;
#pragma unroll
    for (int i = 0; i < 8; ++i) p += y[i] * W[(size_t)l * 512 + lane + 64 * i];
#pragma unroll
    for (int off = 32; off; off >>= 1) p += __shfl_down(p, off, 64);
    if (lane == 0) out[(size_t)row * LL + l] = p + lb[l];
  }
}

// ---------------------------------------------------------------------------
// CRF numerator + denominator + loss. One block of 256 threads.
__global__ __launch_bounds__(256) void crf_kernel(
    const float* __restrict__ logits, const int* __restrict__ labels,
    const int* __restrict__ mask, const float* __restrict__ cs,
    const float* __restrict__ ce, const float* __restrict__ ct,
    float* __restrict__ loss_out) {
  __shared__ float trans[9][12];
  __shared__ float alpha[2][BB][12];
  __shared__ float numsh[BB];
  __shared__ float res[BB];
  int tid = threadIdx.x;
  int b = tid >> 4;
  int i = tid & 15;
  if (tid < 81) trans[tid / 9][tid % 9] = ct[tid];
  __syncthreads();
  const float* lg = logits + (size_t)b * SS * LL;
  const int* lbp = labels + (size_t)b * SS;
  const int* mk = mask + (size_t)b * SS;

  float np = 0.f;
  int msum = 0;
  for (int t = i; t < SS; t += 16) {
    msum += mk[t];
    if (t == 0) {
      int l0 = lbp[0];
      np += cs[l0] + lg[l0];
    } else {
      float m = (float)mk[t];
      np += (trans[lbp[t - 1]][lbp[t]] + lg[(size_t)t * LL + lbp[t]]) * m;
    }
  }
#pragma unroll
  for (int off = 8; off; off >>= 1) {
    np += __shfl_down(np, off, 16);
    msum += __shfl_down(msum, off, 16);
  }
  if (i == 0) {
    int last = msum - 1;
    numsh[b] = np + ce[lbp[last]];
  }

  if (i < LL) alpha[0][b][i] = cs[i] + lg[i];
  int cur = 0;
  for (int t = 1; t < SS; ++t) {
    if (i < LL) {
      float e = lg[(size_t)t * LL + i];
      float av[9];
      float mmax = -1e30f;
#pragma unroll
      for (int p = 0; p < LL; ++p) {
        float vv = alpha[cur][b][p] + trans[p][i];
        av[p] = vv;
        mmax = fmaxf(mmax, vv);
      }
      float ssum = 0.f;
#pragma unroll
      for (int p = 0; p < LL; ++p) ssum += __expf(av[p] - mmax);
      float anew = e + mmax + logf(ssum);
      float aold = alpha[cur][b][i];
      alpha[cur ^ 1][b][i] = (mk[t] > 0) ? anew : aold;
    }
    cur ^= 1;
  }
  if (i == 0) {
    float arr[9];
    float m2 = -1e30f;
#pragma unroll
    for (int cc = 0; cc < LL; ++cc) {
      arr[cc] = alpha[cur][b][cc] + ce[cc];
      m2 = fmaxf(m2, arr[cc]);
    }
    float ssd = 0.f;
#pragma unroll
    for (int cc = 0; cc < LL; ++cc) ssd += __expf(arr[cc] - m2);
    float denom = m2 + logf(ssd);
    res[b] = numsh[b] - denom;
  }
  __syncthreads();
  if (tid == 0) {
    float Lsum = 0.f;
    for (int b2 = 0; b2 < BB; ++b2) Lsum += res[b2];
    loss_out[0] = -Lsum;
  }
}

// ---------------------------------------------------------------------------
extern "C" void kernel_launch(void* const* d_in, const int* in_sizes, int n_in,
                              void* d_out, int out_size, void* d_ws, size_t ws_size,
                              hipStream_t stream) {
  const int* input_ids = (const int*)d_in[0];
  const int* attn_mask = (const int*)d_in[1];
  const int* labels = (const int*)d_in[2];
  const float* embedding = (const float*)d_in[3];
  const float* w_ih_l0 = (const float*)d_in[4];
  const float* w_ih_rest = (const float*)d_in[5];
  const float* w_hh = (const float*)d_in[6];
  const float* bvec = (const float*)d_in[7];
  const float* ln_g = (const float*)d_in[8];
  const float* ln_b = (const float*)d_in[9];
  const float* lin_w = (const float*)d_in[10];
  const float* lin_b = (const float*)d_in[11];
  const float* crf_start = (const float*)d_in[12];
  const float* crf_end = (const float*)d_in[13];
  const float* crf_trans = (const float*)d_in[14];
  float* out = (float*)d_out;
  char* base = (char*)d_ws;

  unsigned short* x0    = (unsigned short*)(base);                        // 2 MB
  unsigned short* xoutA = (unsigned short*)(base + (2u << 20));           // 4 MB
  unsigned short* xoutB = (unsigned short*)(base + (6u << 20));           // 4 MB
  unsigned short* xgP   = (unsigned short*)(base + (10u << 20));          // 16 MB
  long*           wfrag = (long*)(base + (26u << 20));                    // 512 KB
  float*          biasP = (float*)(base + (26u << 20) + (512u << 10));    // 8 KB

  embed_bf16<<<ROWS, 256, 0, stream>>>(input_ids, embedding, x0);

  const unsigned short* cur = x0;
  unsigned short* nxt = xoutA;
  for (int l = 0; l < 4; ++l) {
    int K = l ? 512 : 256;
    const float* wih = l ? (w_ih_rest + (size_t)(l - 1) * 2 * 1024 * 512) : w_ih_l0;
    pack_whh_fp8<<<dim3(64, 8, 2), 64, 0, stream>>>(
        w_hh + (size_t)l * 2 * 1024 * 256, (unsigned long long*)wfrag);
    bias_perm<<<8, 256, 0, stream>>>(bvec + (size_t)l * 4096, biasP);
    gemm_xg_bf16<<<dim3(16, 64, 2), 256, 0, stream>>>(cur, K, wih, biasP, xgP);
    lstm_fp8<<<8, 512, 0, stream>>>(xgP, wfrag, nxt);
    cur = nxt;
    nxt = (nxt == xoutA) ? xoutB : xoutA;
  }

  ln_logits<<<ROWS, 64, 0, stream>>>(cur, ln_g, ln_b, lin_w, lin_b, out);
  crf_kernel<<<1, 256, 0, stream>>>(out, labels, attn_mask, crf_start, crf_end,
                                    crf_trans, out + (size_t)ROWS * LL);
}

// Round 5
// 1623.315 us; speedup vs baseline: 6.4544x; 1.3252x over previous
//
#include <hip/hip_runtime.h>
#include <math.h>

// Problem constants: B=16, S=256, E=256, H=256, V=50000, L=9
#define BB 16
#define SS 256
#define LL 9
#define ROWS 4096
#define APITCH 40      // bf16 elems per LDS row in GEMM (80 B)

typedef __attribute__((ext_vector_type(8))) short short8;   // 8 bf16
typedef __attribute__((ext_vector_type(4))) float f32x4;    // MFMA acc
typedef __attribute__((ext_vector_type(8))) int i32x8;      // 32B MX fragment

#define WSCALE 1024.0f
#define HSCALE 256.0f
// dequant 2^-18 folded into MX scale_b: e8m0 byte 127-18 = 109 = 0x6D
#define SCALE_ONE 0x7F7F7F7Fu
#define SCALE_KINV 0x6D6D6D6Du
#define LOG2E  1.44269504f

__device__ __forceinline__ unsigned short f2bf(float f) {
  unsigned u = __float_as_uint(f);
  return (unsigned short)((u + 0x7FFF + ((u >> 16) & 1)) >> 16);  // RNE
}
__device__ __forceinline__ float bf2f(unsigned short s) {
  return __uint_as_float(((unsigned)s) << 16);
}
__device__ __forceinline__ float sigmoid_fast(float x) {
  return __builtin_amdgcn_rcpf(1.0f + __builtin_amdgcn_exp2f(-LOG2E * x));
}
__device__ __forceinline__ float tanh_fast(float x) {
  float a = fabsf(x);
  float e = __builtin_amdgcn_exp2f(-2.0f * LOG2E * a);
  float r = (1.0f - e) * __builtin_amdgcn_rcpf(1.0f + e);
  return __builtin_copysignf(r, x);
}

// ---------------------------------------------------------------------------
// Embedding gather -> bf16 x0 [4096][256]
__global__ __launch_bounds__(256) void embed_bf16(
    const int* __restrict__ ids, const float* __restrict__ emb,
    unsigned short* __restrict__ x0) {
  int row = blockIdx.x;
  int id = ids[row];
  x0[(size_t)row * 256 + threadIdx.x] = f2bf(emb[(size_t)id * 256 + threadIdx.x]);
}

// ---------------------------------------------------------------------------
// Pack w_hh (one layer) into fp8 e4m3 MX B-fragments (K=128), scaled by WSCALE.
// wfrag[dir][nb(64)][ks2(2)][lane(64)][32B]:
//   byte j = W[dir][n=nb*16+(lane&15)][k=ks2*128+(lane>>4)*32+j] * WSCALE
__global__ __launch_bounds__(64) void pack_whh_mx(
    const float* __restrict__ w, unsigned* __restrict__ wfrag) {
  int nb = blockIdx.x, ks2 = blockIdx.y, dir = blockIdx.z;
  int lane = threadIdx.x, qq = lane >> 4, col = lane & 15;
  const float* wp = w + (size_t)dir * 1024 * 256 + (size_t)(nb * 16 + col) * 256 +
                    ks2 * 128 + qq * 32;
  unsigned* op = wfrag + (((size_t)(dir * 64 + nb) * 2 + ks2) * 64 + lane) * 8;
#pragma unroll
  for (int u = 0; u < 8; ++u) {
    float v0 = wp[u * 4 + 0] * WSCALE, v1 = wp[u * 4 + 1] * WSCALE;
    float v2 = wp[u * 4 + 2] * WSCALE, v3 = wp[u * 4 + 3] * WSCALE;
    unsigned pk = __builtin_amdgcn_cvt_pk_fp8_f32(v0, v1, 0, false);
    pk = __builtin_amdgcn_cvt_pk_fp8_f32(v2, v3, pk, true);
    op[u] = pk;
  }
}

// ---------------------------------------------------------------------------
// biasP[dir][n'] = b_ih[n] + b_hh[n],  n' = j*4+g, n = g*256+j
__global__ __launch_bounds__(256) void bias_perm(
    const float* __restrict__ b2, float* __restrict__ biasP) {
  int i = blockIdx.x * 256 + threadIdx.x;  // 0..2047
  int dir = i >> 10, np = i & 1023;
  int n = ((np & 3) << 8) + (np >> 2);
  biasP[i] = b2[dir * 2048 + n] + b2[dir * 2048 + 1024 + n];
}

// ---------------------------------------------------------------------------
// bf16 MFMA GEMM: xgP[dir][row][n'] = sum_k A[row][k]*Wih[dir][n(n')][k] + biasP
__global__ __launch_bounds__(256) void gemm_xg_bf16(
    const unsigned short* __restrict__ A, int K,
    const float* __restrict__ Wih,
    const float* __restrict__ biasP,
    unsigned short* __restrict__ xgP) {
  int dir = blockIdx.z;
  const float* Bw = Wih + (size_t)dir * 1024 * K;
  int n0 = blockIdx.x * 64, m0 = blockIdx.y * 64;
  int tid = threadIdx.x;
  int wv = tid >> 6, lane = tid & 63, quad = lane >> 4, col = lane & 15;
  __shared__ unsigned short As[64 * APITCH];
  __shared__ unsigned short Bs[64 * APITCH];
  int lr = tid >> 2;
  int lk = (tid & 3) * 8;
  int nprime = n0 + lr;
  int nphys = ((nprime & 3) << 8) + (nprime >> 2);
  f32x4 acc[4];
#pragma unroll
  for (int nt = 0; nt < 4; ++nt) acc[nt] = (f32x4){0.f, 0.f, 0.f, 0.f};

  for (int k0 = 0; k0 < K; k0 += 32) {
    short8 av = *(const short8*)&A[(size_t)(m0 + lr) * K + k0 + lk];
    float4 b0 = *(const float4*)&Bw[(size_t)nphys * K + k0 + lk];
    float4 b1 = *(const float4*)&Bw[(size_t)nphys * K + k0 + lk + 4];
    short8 bv;
    bv[0] = (short)f2bf(b0.x); bv[1] = (short)f2bf(b0.y);
    bv[2] = (short)f2bf(b0.z); bv[3] = (short)f2bf(b0.w);
    bv[4] = (short)f2bf(b1.x); bv[5] = (short)f2bf(b1.y);
    bv[6] = (short)f2bf(b1.z); bv[7] = (short)f2bf(b1.w);
    __syncthreads();
    *(short8*)&As[lr * APITCH + lk] = av;
    *(short8*)&Bs[lr * APITCH + lk] = bv;
    __syncthreads();
    short8 af = *(const short8*)&As[(wv * 16 + col) * APITCH + quad * 8];
#pragma unroll
    for (int nt = 0; nt < 4; ++nt) {
      short8 bf = *(const short8*)&Bs[(nt * 16 + col) * APITCH + quad * 8];
      acc[nt] = __builtin_amdgcn_mfma_f32_16x16x32_bf16(af, bf, acc[nt], 0, 0, 0);
    }
  }
#pragma unroll
  for (int nt = 0; nt < 4; ++nt) {
    int np = n0 + nt * 16 + col;
    float bia = biasP[dir * 1024 + np];
#pragma unroll
    for (int r = 0; r < 4; ++r) {
      int row = m0 + wv * 16 + quad * 4 + r;
      xgP[((size_t)dir * ROWS + row) * 1024 + np] = f2bf(acc[nt][r] + bia);
    }
  }
}

// ---------------------------------------------------------------------------
// MX-fp8 (K=128) MFMA LSTM recurrence. grid = 8 blocks (bg*2+dir), 4 batches
// per block, 512 threads (8 waves, 2/SIMD). W_hh register-resident as MX
// B-fragments (128 VGPR). H stored in LDS in A-FRAGMENT ORDER (conflict-free
// 32B/lane contiguous reads). Dequant 2^-18 folded into MX scale_b.
// Per step: 16 MFMA/wave -> gates to swizzled gbuf (quad0) -> barrier ->
// epilogue 2 cells/thread -> H bytes to Hfrag[nxt] -> barrier. xout store of
// step t is deferred to the top of step t+1 (hidden under MFMA phase).
__global__ __launch_bounds__(512, 2) void lstm_mx(
    const unsigned short* __restrict__ xgP,   // [2][4096][1024] bf16 n'=j*4+g
    const unsigned* __restrict__ wfrag,       // [2][64][2][64][8] dwords
    unsigned short* __restrict__ xout) {      // [4096][512] bf16
  int dir = blockIdx.x & 1;
  int bg = blockIdx.x >> 1;            // batches bg*4 .. bg*4+3
  int tid = threadIdx.x;
  int wv = tid >> 6, lane = tid & 63;
  int quad = lane >> 4, col = lane & 15;

  // Hfrag[buf][ks2*2048 + lane*32 + j] = H[b=lane&15][k=ks2*128+(lane>>4)*32+j]
  __shared__ __align__(16) unsigned char Hfrag[2][4096];
  __shared__ __align__(16) float gbuf[4 * 256 * 4];   // swizzled [b][slot][g]

  {  // zero both H buffers (batch rows 4..15 stay zero forever)
    int* hz = (int*)&Hfrag[0][0];
    for (int i = tid; i < 2048; i += 512) hz[i] = 0;
  }

  // weight fragments, loaded once: wf[hbi][g][ks2]
  i32x8 wf[2][4][2];
#pragma unroll
  for (int hbi = 0; hbi < 2; ++hbi)
#pragma unroll
    for (int g = 0; g < 4; ++g) {
      int nb = g * 16 + 2 * wv + hbi;
#pragma unroll
      for (int ks2 = 0; ks2 < 2; ++ks2)
        wf[hbi][g][ks2] = *(const i32x8*)(wfrag +
            (((size_t)(dir * 64 + nb) * 2 + ks2) * 64 + lane) * 8);
    }

  // epilogue mapping: thread -> cells (2m, 2m+1) of local batch eb
  int eb = tid >> 7;                 // 0..3
  int m = tid & 127;
  int j0 = 2 * m;
  const unsigned short* xq_base =
      xgP + ((size_t)dir * ROWS + (size_t)(bg * 4 + eb) * SS) * 1024 + j0 * 4;
  unsigned short* xo_base = xout + (size_t)(bg * 4 + eb) * SS * 512 + dir * 256 + j0;
  // H-write offset within a buffer (2 adjacent fp8 bytes for cells j0, j0+1)
  int hoff = ((j0 >> 7) << 11) + (((j0 & 127) >> 5) << 9) + (eb << 5) + (j0 & 31);

  float cst[2] = {0.f, 0.f};
  unsigned prev_ob = 0;
  int prevpos = -1;
  int cur = 0;
  __syncthreads();

  for (int t = 0; t < SS; ++t) {
    int pos = dir ? (SS - 1 - t) : t;
    // deferred xout store from previous step (drains under MFMA phase)
    if (prevpos >= 0) *(unsigned*)(xo_base + (size_t)prevpos * 512) = prev_ob;
    // prefetch xg for this thread's 2 cells (16 B)
    short8 xq = *(const short8*)(xq_base + (size_t)pos * 1024);

    // ---- MFMA phase: A-fragments are contiguous 32B/lane
    i32x8 af0 = *(const i32x8*)&Hfrag[cur][lane * 32];
    i32x8 af1 = *(const i32x8*)&Hfrag[cur][2048 + lane * 32];
    f32x4 acc[2][4];
#pragma unroll
    for (int hbi = 0; hbi < 2; ++hbi)
#pragma unroll
      for (int g = 0; g < 4; ++g) {
        f32x4 a = (f32x4){0.f, 0.f, 0.f, 0.f};
        a = __builtin_amdgcn_mfma_scale_f32_16x16x128_f8f6f4(
                af0, wf[hbi][g][0], a, 0, 0, 0, SCALE_ONE, 0, SCALE_KINV);
        a = __builtin_amdgcn_mfma_scale_f32_16x16x128_f8f6f4(
                af1, wf[hbi][g][1], a, 0, 0, 0, SCALE_ONE, 0, SCALE_KINV);
        acc[hbi][g] = a;
      }

    // ---- raw gates -> swizzled gbuf (quad0 lanes hold batch rows 0..3)
    if (quad == 0) {
#pragma unroll
      for (int hbi = 0; hbi < 2; ++hbi) {
        int j = 16 * (2 * wv + hbi) + col;
        int slot = ((j & 1) << 7) + (j >> 1);
#pragma unroll
        for (int r = 0; r < 4; ++r) {
          float4 v = make_float4(acc[hbi][0][r], acc[hbi][1][r],
                                 acc[hbi][2][r], acc[hbi][3][r]);
          *(float4*)&gbuf[(r * 256 + slot) * 4] = v;
        }
      }
    }
    __syncthreads();

    // ---- epilogue: cells 2m (slot m) and 2m+1 (slot 128+m)
    int nxt = cur ^ 1;
    float4 gv0 = *(const float4*)&gbuf[(eb * 256 + m) * 4];
    float4 gv1 = *(const float4*)&gbuf[(eb * 256 + 128 + m) * 4];
    float h01[2];
    {
      float gi = gv0.x + bf2f((unsigned short)xq[0]);
      float gf = gv0.y + bf2f((unsigned short)xq[1]);
      float gg = gv0.z + bf2f((unsigned short)xq[2]);
      float go = gv0.w + bf2f((unsigned short)xq[3]);
      float c = sigmoid_fast(gf) * cst[0] + sigmoid_fast(gi) * tanh_fast(gg);
      cst[0] = c;
      h01[0] = sigmoid_fast(go) * tanh_fast(c);
    }
    {
      float gi = gv1.x + bf2f((unsigned short)xq[4]);
      float gf = gv1.y + bf2f((unsigned short)xq[5]);
      float gg = gv1.z + bf2f((unsigned short)xq[6]);
      float go = gv1.w + bf2f((unsigned short)xq[7]);
      float c = sigmoid_fast(gf) * cst[1] + sigmoid_fast(gi) * tanh_fast(gg);
      cst[1] = c;
      h01[1] = sigmoid_fast(go) * tanh_fast(c);
    }
    unsigned pk = __builtin_amdgcn_cvt_pk_fp8_f32(h01[0] * HSCALE, h01[1] * HSCALE, 0, false);
    *(unsigned short*)&Hfrag[nxt][hoff] = (unsigned short)(pk & 0xFFFF);
    prev_ob = (unsigned)f2bf(h01[0]) | ((unsigned)f2bf(h01[1]) << 16);
    prevpos = pos;
    __syncthreads();
    cur = nxt;
  }
  // final deferred store
  *(unsigned*)(xo_base + (size_t)prevpos * 512) = prev_ob;
}

// ---------------------------------------------------------------------------
// LayerNorm + 9-way linear. One wave per row. X is bf16 [4096][512].
__global__ __launch_bounds__(64) void ln_logits(
    const unsigned short* __restrict__ X, const float* __restrict__ g,
    const float* __restrict__ bt, const float* __restrict__ W,
    const float* __restrict__ lb, float* __restrict__ out) {
  int row = blockIdx.x;
  int lane = threadIdx.x;
  const unsigned short* x = X + (size_t)row * 512;
  float v[8];
  float s = 0.f, s2 = 0.f;
#pragma unroll
  for (int i = 0; i < 8; ++i) {
    v[i] = bf2f(x[lane + 64 * i]);
    s += v[i];
    s2 += v[i] * v[i];
  }
#pragma unroll
  for (int off = 32; off; off >>= 1) {
    s += __shfl_down(s, off, 64);
    s2 += __shfl_down(s2, off, 64);
  }
  s = __shfl(s, 0, 64);
  s2 = __shfl(s2, 0, 64);
  float mu = s * (1.f / 512.f);
  float var = s2 * (1.f / 512.f) - mu * mu;
  float rstd = rsqrtf(var + 1e-5f);
  float y[8];
#pragma unroll
  for (int i = 0; i < 8; ++i) {
    int e = lane + 64 * i;
    y[i] = (v[i] - mu) * rstd * g[e] + bt[e];
  }
  for (int l = 0; l < LL; ++l) {
    float p = 0.f;
#pragma unroll
    for (int i = 0; i < 8; ++i) p += y[i] * W[(size_t)l * 512 + lane + 64 * i];
#pragma unroll
    for (int off = 32; off; off >>= 1) p += __shfl_down(p, off, 64);
    if (lane == 0) out[(size_t)row * LL + l] = p + lb[l];
  }
}

// ---------------------------------------------------------------------------
// CRF numerator + denominator + loss. One block of 256 threads.
__global__ __launch_bounds__(256) void crf_kernel(
    const float* __restrict__ logits, const int* __restrict__ labels,
    const int* __restrict__ mask, const float* __restrict__ cs,
    const float* __restrict__ ce, const float* __restrict__ ct,
    float* __restrict__ loss_out) {
  __shared__ float trans[9][12];
  __shared__ float alpha[2][BB][12];
  __shared__ float numsh[BB];
  __shared__ float res[BB];
  int tid = threadIdx.x;
  int b = tid >> 4;
  int i = tid & 15;
  if (tid < 81) trans[tid / 9][tid % 9] = ct[tid];
  __syncthreads();
  const float* lg = logits + (size_t)b * SS * LL;
  const int* lbp = labels + (size_t)b * SS;
  const int* mk = mask + (size_t)b * SS;

  float np = 0.f;
  int msum = 0;
  for (int t = i; t < SS; t += 16) {
    msum += mk[t];
    if (t == 0) {
      int l0 = lbp[0];
      np += cs[l0] + lg[l0];
    } else {
      float m = (float)mk[t];
      np += (trans[lbp[t - 1]][lbp[t]] + lg[(size_t)t * LL + lbp[t]]) * m;
    }
  }
#pragma unroll
  for (int off = 8; off; off >>= 1) {
    np += __shfl_down(np, off, 16);
    msum += __shfl_down(msum, off, 16);
  }
  if (i == 0) {
    int last = msum - 1;
    numsh[b] = np + ce[lbp[last]];
  }

  if (i < LL) alpha[0][b][i] = cs[i] + lg[i];
  int cur = 0;
  for (int t = 1; t < SS; ++t) {
    if (i < LL) {
      float e = lg[(size_t)t * LL + i];
      float av[9];
      float mmax = -1e30f;
#pragma unroll
      for (int p = 0; p < LL; ++p) {
        float vv = alpha[cur][b][p] + trans[p][i];
        av[p] = vv;
        mmax = fmaxf(mmax, vv);
      }
      float ssum = 0.f;
#pragma unroll
      for (int p = 0; p < LL; ++p) ssum += __expf(av[p] - mmax);
      float anew = e + mmax + logf(ssum);
      float aold = alpha[cur][b][i];
      alpha[cur ^ 1][b][i] = (mk[t] > 0) ? anew : aold;
    }
    cur ^= 1;
  }
  if (i == 0) {
    float arr[9];
    float m2 = -1e30f;
#pragma unroll
    for (int cc = 0; cc < LL; ++cc) {
      arr[cc] = alpha[cur][b][cc] + ce[cc];
      m2 = fmaxf(m2, arr[cc]);
    }
    float ssd = 0.f;
#pragma unroll
    for (int cc = 0; cc < LL; ++cc) ssd += __expf(arr[cc] - m2);
    float denom = m2 + logf(ssd);
    res[b] = numsh[b] - denom;
  }
  __syncthreads();
  if (tid == 0) {
    float Lsum = 0.f;
    for (int b2 = 0; b2 < BB; ++b2) Lsum += res[b2];
    loss_out[0] = -Lsum;
  }
}

// ---------------------------------------------------------------------------
extern "C" void kernel_launch(void* const* d_in, const int* in_sizes, int n_in,
                              void* d_out, int out_size, void* d_ws, size_t ws_size,
                              hipStream_t stream) {
  const int* input_ids = (const int*)d_in[0];
  const int* attn_mask = (const int*)d_in[1];
  const int* labels = (const int*)d_in[2];
  const float* embedding = (const float*)d_in[3];
  const float* w_ih_l0 = (const float*)d_in[4];
  const float* w_ih_rest = (const float*)d_in[5];
  const float* w_hh = (const float*)d_in[6];
  const float* bvec = (const float*)d_in[7];
  const float* ln_g = (const float*)d_in[8];
  const float* ln_b = (const float*)d_in[9];
  const float* lin_w = (const float*)d_in[10];
  const float* lin_b = (const float*)d_in[11];
  const float* crf_start = (const float*)d_in[12];
  const float* crf_end = (const float*)d_in[13];
  const float* crf_trans = (const float*)d_in[14];
  float* out = (float*)d_out;
  char* base = (char*)d_ws;

  unsigned short* x0    = (unsigned short*)(base);                        // 2 MB
  unsigned short* xoutA = (unsigned short*)(base + (2u << 20));           // 4 MB
  unsigned short* xoutB = (unsigned short*)(base + (6u << 20));           // 4 MB
  unsigned short* xgP   = (unsigned short*)(base + (10u << 20));          // 16 MB
  unsigned*       wfrag = (unsigned*)(base + (26u << 20));                // 512 KB
  float*          biasP = (float*)(base + (26u << 20) + (512u << 10));    // 8 KB

  embed_bf16<<<ROWS, 256, 0, stream>>>(input_ids, embedding, x0);

  const unsigned short* cur = x0;
  unsigned short* nxt = xoutA;
  for (int l = 0; l < 4; ++l) {
    int K = l ? 512 : 256;
    const float* wih = l ? (w_ih_rest + (size_t)(l - 1) * 2 * 1024 * 512) : w_ih_l0;
    pack_whh_mx<<<dim3(64, 2, 2), 64, 0, stream>>>(
        w_hh + (size_t)l * 2 * 1024 * 256, wfrag);
    bias_perm<<<8, 256, 0, stream>>>(bvec + (size_t)l * 4096, biasP);
    gemm_xg_bf16<<<dim3(16, 64, 2), 256, 0, stream>>>(cur, K, wih, biasP, xgP);
    lstm_mx<<<8, 512, 0, stream>>>(xgP, wfrag, nxt);
    cur = nxt;
    nxt = (nxt == xoutA) ? xoutB : xoutA;
  }

  ln_logits<<<ROWS, 64, 0, stream>>>(cur, ln_g, ln_b, lin_w, lin_b, out);
  crf_kernel<<<1, 256, 0, stream>>>(out, labels, attn_mask, crf_start, crf_end,
                                    crf_trans, out + (size_t)ROWS * LL);
}

// Round 6
// 1272.231 us; speedup vs baseline: 8.2355x; 1.2760x over previous
//
#include <hip/hip_runtime.h>
#include <math.h>

// Problem constants: B=16, S=256, E=256, H=256, V=50000, L=9
#define BB 16
#define SS 256
#define LL 9
#define ROWS 4096
#define APITCH 40      // bf16 elems per LDS row in GEMM (80 B)
#define HP 272         // bytes per batch row of H in LDS (fp8): 2 words/bank on b128 reads

typedef __attribute__((ext_vector_type(8))) short short8;   // 8 bf16
typedef __attribute__((ext_vector_type(4))) float f32x4;    // MFMA acc
typedef __attribute__((ext_vector_type(8))) int i32x8;      // 32B MX fragment

#define WSCALE 1024.0f
#define HSCALE 256.0f
// dequant 2^-18 folded into MX scale_b: e8m0 byte 127-18 = 109 = 0x6D
#define SCALE_ONE 0x7F7F7F7Fu
#define SCALE_KINV 0x6D6D6D6Du
#define LOG2E  1.44269504f

__device__ __forceinline__ unsigned short f2bf(float f) {
  unsigned u = __float_as_uint(f);
  return (unsigned short)((u + 0x7FFF + ((u >> 16) & 1)) >> 16);  // RNE
}
__device__ __forceinline__ float bf2f(unsigned short s) {
  return __uint_as_float(((unsigned)s) << 16);
}
// minimal-instr activations: no div, no copysign, saturate correctly via inf/0
__device__ __forceinline__ float sigmoid_fast(float x) {
  return __builtin_amdgcn_rcpf(1.0f + __builtin_amdgcn_exp2f(-LOG2E * x));
}
__device__ __forceinline__ float tanh_fast(float x) {
  // tanh(x) = 1 - 2/(e^{2x}+1)
  float e = __builtin_amdgcn_exp2f((2.0f * LOG2E) * x);
  return fmaf(-2.0f, __builtin_amdgcn_rcpf(1.0f + e), 1.0f);
}

// ---------------------------------------------------------------------------
// Embedding gather -> bf16 x0 [4096][256]
__global__ __launch_bounds__(256) void embed_bf16(
    const int* __restrict__ ids, const float* __restrict__ emb,
    unsigned short* __restrict__ x0) {
  int row = blockIdx.x;
  int id = ids[row];
  x0[(size_t)row * 256 + threadIdx.x] = f2bf(emb[(size_t)id * 256 + threadIdx.x]);
}

// ---------------------------------------------------------------------------
// Pack w_hh (one layer) into fp8 e4m3 MX B-fragments (K=128), scaled by WSCALE.
// wfrag[dir][nb(64)][ks2(2)][lane(64)][32B]:
//   byte j = W[dir][n=nb*16+(lane&15)][k=ks2*128+(lane>>4)*32+j] * WSCALE
__global__ __launch_bounds__(64) void pack_whh_mx(
    const float* __restrict__ w, unsigned* __restrict__ wfrag) {
  int nb = blockIdx.x, ks2 = blockIdx.y, dir = blockIdx.z;
  int lane = threadIdx.x, qq = lane >> 4, col = lane & 15;
  const float* wp = w + (size_t)dir * 1024 * 256 + (size_t)(nb * 16 + col) * 256 +
                    ks2 * 128 + qq * 32;
  unsigned* op = wfrag + (((size_t)(dir * 64 + nb) * 2 + ks2) * 64 + lane) * 8;
#pragma unroll
  for (int u = 0; u < 8; ++u) {
    float v0 = wp[u * 4 + 0] * WSCALE, v1 = wp[u * 4 + 1] * WSCALE;
    float v2 = wp[u * 4 + 2] * WSCALE, v3 = wp[u * 4 + 3] * WSCALE;
    unsigned pk = __builtin_amdgcn_cvt_pk_fp8_f32(v0, v1, 0, false);
    pk = __builtin_amdgcn_cvt_pk_fp8_f32(v2, v3, pk, true);
    op[u] = pk;
  }
}

// ---------------------------------------------------------------------------
// biasP[dir][n'] = b_ih[n] + b_hh[n],  n' = j*4+g, n = g*256+j
__global__ __launch_bounds__(256) void bias_perm(
    const float* __restrict__ b2, float* __restrict__ biasP) {
  int i = blockIdx.x * 256 + threadIdx.x;  // 0..2047
  int dir = i >> 10, np = i & 1023;
  int n = ((np & 3) << 8) + (np >> 2);
  biasP[i] = b2[dir * 2048 + n] + b2[dir * 2048 + 1024 + n];
}

// ---------------------------------------------------------------------------
// bf16 MFMA GEMM: xgP[dir][row][n'] = sum_k A[row][k]*Wih[dir][n(n')][k] + biasP
__global__ __launch_bounds__(256) void gemm_xg_bf16(
    const unsigned short* __restrict__ A, int K,
    const float* __restrict__ Wih,
    const float* __restrict__ biasP,
    unsigned short* __restrict__ xgP) {
  int dir = blockIdx.z;
  const float* Bw = Wih + (size_t)dir * 1024 * K;
  int n0 = blockIdx.x * 64, m0 = blockIdx.y * 64;
  int tid = threadIdx.x;
  int wv = tid >> 6, lane = tid & 63, quad = lane >> 4, col = lane & 15;
  __shared__ unsigned short As[64 * APITCH];
  __shared__ unsigned short Bs[64 * APITCH];
  int lr = tid >> 2;
  int lk = (tid & 3) * 8;
  int nprime = n0 + lr;
  int nphys = ((nprime & 3) << 8) + (nprime >> 2);
  f32x4 acc[4];
#pragma unroll
  for (int nt = 0; nt < 4; ++nt) acc[nt] = (f32x4){0.f, 0.f, 0.f, 0.f};

  for (int k0 = 0; k0 < K; k0 += 32) {
    short8 av = *(const short8*)&A[(size_t)(m0 + lr) * K + k0 + lk];
    float4 b0 = *(const float4*)&Bw[(size_t)nphys * K + k0 + lk];
    float4 b1 = *(const float4*)&Bw[(size_t)nphys * K + k0 + lk + 4];
    short8 bv;
    bv[0] = (short)f2bf(b0.x); bv[1] = (short)f2bf(b0.y);
    bv[2] = (short)f2bf(b0.z); bv[3] = (short)f2bf(b0.w);
    bv[4] = (short)f2bf(b1.x); bv[5] = (short)f2bf(b1.y);
    bv[6] = (short)f2bf(b1.z); bv[7] = (short)f2bf(b1.w);
    __syncthreads();
    *(short8*)&As[lr * APITCH + lk] = av;
    *(short8*)&Bs[lr * APITCH + lk] = bv;
    __syncthreads();
    short8 af = *(const short8*)&As[(wv * 16 + col) * APITCH + quad * 8];
#pragma unroll
    for (int nt = 0; nt < 4; ++nt) {
      short8 bf = *(const short8*)&Bs[(nt * 16 + col) * APITCH + quad * 8];
      acc[nt] = __builtin_amdgcn_mfma_f32_16x16x32_bf16(af, bf, acc[nt], 0, 0, 0);
    }
  }
#pragma unroll
  for (int nt = 0; nt < 4; ++nt) {
    int np = n0 + nt * 16 + col;
    float bia = biasP[dir * 1024 + np];
#pragma unroll
    for (int r = 0; r < 4; ++r) {
      int row = m0 + wv * 16 + quad * 4 + r;
      xgP[((size_t)dir * ROWS + row) * 1024 + np] = f2bf(acc[nt][r] + bia);
    }
  }
}

// ---------------------------------------------------------------------------
// MX-fp8 (K=128) MFMA LSTM recurrence, batch-replicated A-operand.
// grid = 8 blocks (bg*2+dir), 4 batches per block, 512 threads (8 waves, 2/SIMD).
// H stored compactly in LDS as [4][HP] fp8; the A-fragment READ replicates each
// batch 4x in M (lane reads H[(lane&15)>>2]) so C row m holds gates of batch
// m>>2 -> every lane's acc reg 0 holds all four gates of cell
// (b=quad, j=(2wv+hbi)*16+col). Epilogue fully in-register: no gbuf, no
// redistribution barrier -> ONE barrier per step. xout stores deferred one step.
__global__ __launch_bounds__(512, 2) void lstm_mx(
    const unsigned short* __restrict__ xgP,   // [2][4096][1024] bf16 n'=j*4+g
    const unsigned* __restrict__ wfrag,       // [2][64][2][64][8] dwords
    unsigned short* __restrict__ xout) {      // [4096][512] bf16
  int dir = blockIdx.x & 1;
  int bg = blockIdx.x >> 1;            // batches bg*4 .. bg*4+3
  int tid = threadIdx.x;
  int wv = tid >> 6, lane = tid & 63;
  int quad = lane >> 4, col = lane & 15;

  __shared__ __align__(16) unsigned char Hfrag[2][4 * HP];

  {  // zero both H buffers
    int* hz = (int*)&Hfrag[0][0];
    for (int i = tid; i < 2 * HP; i += 512) hz[i] = 0;   // 2*4*HP/4 = 2*HP ints
  }

  // weight fragments, loaded once: wf[hbi][g][ks2]  (128 VGPR)
  i32x8 wf[2][4][2];
#pragma unroll
  for (int hbi = 0; hbi < 2; ++hbi)
#pragma unroll
    for (int g = 0; g < 4; ++g) {
      int nb = g * 16 + 2 * wv + hbi;
#pragma unroll
      for (int ks2 = 0; ks2 < 2; ++ks2)
        wf[hbi][g][ks2] = *(const i32x8*)(wfrag +
            (((size_t)(dir * 64 + nb) * 2 + ks2) * 64 + lane) * 8);
    }

  // batch-replicated A-read offset: lane reads H[(lane&15)>>2], k-chunk lane>>4
  int aoff = ((lane & 15) >> 2) * HP + (lane >> 4) * 32;

  // this lane's cells: (b=quad, j0=(2wv)*16+col) and (b=quad, j1=j0+16)
  int j0 = 32 * wv + col;
  const unsigned short* xq_base =
      xgP + ((size_t)dir * ROWS + (size_t)(bg * 4 + quad) * SS) * 1024 + j0 * 4;
  unsigned short* xo_base =
      xout + (size_t)(bg * 4 + quad) * SS * 512 + dir * 256 + j0;

  float cst0 = 0.f, cst1 = 0.f;
  unsigned short ph0 = 0, ph1 = 0;
  int prevpos = -1;
  int cur = 0;
  __syncthreads();

  for (int t = 0; t < SS; ++t) {
    int pos = dir ? (SS - 1 - t) : t;
    // deferred xout stores from previous step (drain under MFMA phase)
    if (prevpos >= 0) {
      xo_base[(size_t)prevpos * 512] = ph0;
      xo_base[(size_t)prevpos * 512 + 16] = ph1;
    }
    // prefetch xg for the 2 cells (gates i,f,g,o contiguous: 8 B each)
    ushort4 xq0 = *(const ushort4*)(xq_base + (size_t)pos * 1024);
    ushort4 xq1 = *(const ushort4*)(xq_base + (size_t)pos * 1024 + 64);

    // ---- MFMA phase (A batch-replicated; 4-way broadcast reads, conflict-free)
    i32x8 af0 = *(const i32x8*)&Hfrag[cur][aoff];
    i32x8 af1 = *(const i32x8*)&Hfrag[cur][aoff + 128];
    f32x4 acc[2][4];
#pragma unroll
    for (int hbi = 0; hbi < 2; ++hbi)
#pragma unroll
      for (int g = 0; g < 4; ++g) {
        f32x4 a = (f32x4){0.f, 0.f, 0.f, 0.f};
        a = __builtin_amdgcn_mfma_scale_f32_16x16x128_f8f6f4(
                af0, wf[hbi][g][0], a, 0, 0, 0, SCALE_ONE, 0, SCALE_KINV);
        a = __builtin_amdgcn_mfma_scale_f32_16x16x128_f8f6f4(
                af1, wf[hbi][g][1], a, 0, 0, 0, SCALE_ONE, 0, SCALE_KINV);
        acc[hbi][g] = a;
      }

    // ---- in-register epilogue: acc reg 0 = batch quad
    int nxt = cur ^ 1;
    float h0, h1;
    {
      float gi = acc[0][0][0] + bf2f(xq0.x);
      float gf = acc[0][1][0] + bf2f(xq0.y);
      float gg = acc[0][2][0] + bf2f(xq0.z);
      float go = acc[0][3][0] + bf2f(xq0.w);
      float c = sigmoid_fast(gf) * cst0 + sigmoid_fast(gi) * tanh_fast(gg);
      cst0 = c;
      h0 = sigmoid_fast(go) * tanh_fast(c);
    }
    {
      float gi = acc[1][0][0] + bf2f(xq1.x);
      float gf = acc[1][1][0] + bf2f(xq1.y);
      float gg = acc[1][2][0] + bf2f(xq1.z);
      float go = acc[1][3][0] + bf2f(xq1.w);
      float c = sigmoid_fast(gf) * cst1 + sigmoid_fast(gi) * tanh_fast(gg);
      cst1 = c;
      h1 = sigmoid_fast(go) * tanh_fast(c);
    }
    unsigned pk = __builtin_amdgcn_cvt_pk_fp8_f32(h0 * HSCALE, h1 * HSCALE, 0, false);
    Hfrag[nxt][quad * HP + j0]      = (unsigned char)(pk & 0xFF);
    Hfrag[nxt][quad * HP + j0 + 16] = (unsigned char)((pk >> 8) & 0xFF);
    ph0 = f2bf(h0);
    ph1 = f2bf(h1);
    prevpos = pos;
    __syncthreads();
    cur = nxt;
  }
  // final deferred stores
  xo_base[(size_t)prevpos * 512] = ph0;
  xo_base[(size_t)prevpos * 512 + 16] = ph1;
}

// ---------------------------------------------------------------------------
// LayerNorm + 9-way linear. One wave per row. X is bf16 [4096][512].
__global__ __launch_bounds__(64) void ln_logits(
    const unsigned short* __restrict__ X, const float* __restrict__ g,
    const float* __restrict__ bt, const float* __restrict__ W,
    const float* __restrict__ lb, float* __restrict__ out) {
  int row = blockIdx.x;
  int lane = threadIdx.x;
  const unsigned short* x = X + (size_t)row * 512;
  float v[8];
  float s = 0.f, s2 = 0.f;
#pragma unroll
  for (int i = 0; i < 8; ++i) {
    v[i] = bf2f(x[lane + 64 * i]);
    s += v[i];
    s2 += v[i] * v[i];
  }
#pragma unroll
  for (int off = 32; off; off >>= 1) {
    s += __shfl_down(s, off, 64);
    s2 += __shfl_down(s2, off, 64);
  }
  s = __shfl(s, 0, 64);
  s2 = __shfl(s2, 0, 64);
  float mu = s * (1.f / 512.f);
  float var = s2 * (1.f / 512.f) - mu * mu;
  float rstd = rsqrtf(var + 1e-5f);
  float y[8];
#pragma unroll
  for (int i = 0; i < 8; ++i) {
    int e = lane + 64 * i;
    y[i] = (v[i] - mu) * rstd * g[e] + bt[e];
  }
  for (int l = 0; l < LL; ++l) {
    float p = 0.f;
#pragma unroll
    for (int i = 0; i < 8; ++i) p += y[i] * W[(size_t)l * 512 + lane + 64 * i];
#pragma unroll
    for (int off = 32; off; off >>= 1) p += __shfl_down(p, off, 64);
    if (lane == 0) out[(size_t)row * LL + l] = p + lb[l];
  }
}

// ---------------------------------------------------------------------------
// CRF numerator + denominator + loss. One block of 256 threads.
__global__ __launch_bounds__(256) void crf_kernel(
    const float* __restrict__ logits, const int* __restrict__ labels,
    const int* __restrict__ mask, const float* __restrict__ cs,
    const float* __restrict__ ce, const float* __restrict__ ct,
    float* __restrict__ loss_out) {
  __shared__ float trans[9][12];
  __shared__ float alpha[2][BB][12];
  __shared__ float numsh[BB];
  __shared__ float res[BB];
  int tid = threadIdx.x;
  int b = tid >> 4;
  int i = tid & 15;
  if (tid < 81) trans[tid / 9][tid % 9] = ct[tid];
  __syncthreads();
  const float* lg = logits + (size_t)b * SS * LL;
  const int* lbp = labels + (size_t)b * SS;
  const int* mk = mask + (size_t)b * SS;

  float np = 0.f;
  int msum = 0;
  for (int t = i; t < SS; t += 16) {
    msum += mk[t];
    if (t == 0) {
      int l0 = lbp[0];
      np += cs[l0] + lg[l0];
    } else {
      float m = (float)mk[t];
      np += (trans[lbp[t - 1]][lbp[t]] + lg[(size_t)t * LL + lbp[t]]) * m;
    }
  }
#pragma unroll
  for (int off = 8; off; off >>= 1) {
    np += __shfl_down(np, off, 16);
    msum += __shfl_down(msum, off, 16);
  }
  if (i == 0) {
    int last = msum - 1;
    numsh[b] = np + ce[lbp[last]];
  }

  if (i < LL) alpha[0][b][i] = cs[i] + lg[i];
  int cur = 0;
  for (int t = 1; t < SS; ++t) {
    if (i < LL) {
      float e = lg[(size_t)t * LL + i];
      float av[9];
      float mmax = -1e30f;
#pragma unroll
      for (int p = 0; p < LL; ++p) {
        float vv = alpha[cur][b][p] + trans[p][i];
        av[p] = vv;
        mmax = fmaxf(mmax, vv);
      }
      float ssum = 0.f;
#pragma unroll
      for (int p = 0; p < LL; ++p) ssum += __expf(av[p] - mmax);
      float anew = e + mmax + logf(ssum);
      float aold = alpha[cur][b][i];
      alpha[cur ^ 1][b][i] = (mk[t] > 0) ? anew : aold;
    }
    cur ^= 1;
  }
  if (i == 0) {
    float arr[9];
    float m2 = -1e30f;
#pragma unroll
    for (int cc = 0; cc < LL; ++cc) {
      arr[cc] = alpha[cur][b][cc] + ce[cc];
      m2 = fmaxf(m2, arr[cc]);
    }
    float ssd = 0.f;
#pragma unroll
    for (int cc = 0; cc < LL; ++cc) ssd += __expf(arr[cc] - m2);
    float denom = m2 + logf(ssd);
    res[b] = numsh[b] - denom;
  }
  __syncthreads();
  if (tid == 0) {
    float Lsum = 0.f;
    for (int b2 = 0; b2 < BB; ++b2) Lsum += res[b2];
    loss_out[0] = -Lsum;
  }
}

// ---------------------------------------------------------------------------
extern "C" void kernel_launch(void* const* d_in, const int* in_sizes, int n_in,
                              void* d_out, int out_size, void* d_ws, size_t ws_size,
                              hipStream_t stream) {
  const int* input_ids = (const int*)d_in[0];
  const int* attn_mask = (const int*)d_in[1];
  const int* labels = (const int*)d_in[2];
  const float* embedding = (const float*)d_in[3];
  const float* w_ih_l0 = (const float*)d_in[4];
  const float* w_ih_rest = (const float*)d_in[5];
  const float* w_hh = (const float*)d_in[6];
  const float* bvec = (const float*)d_in[7];
  const float* ln_g = (const float*)d_in[8];
  const float* ln_b = (const float*)d_in[9];
  const float* lin_w = (const float*)d_in[10];
  const float* lin_b = (const float*)d_in[11];
  const float* crf_start = (const float*)d_in[12];
  const float* crf_end = (const float*)d_in[13];
  const float* crf_trans = (const float*)d_in[14];
  float* out = (float*)d_out;
  char* base = (char*)d_ws;

  unsigned short* x0    = (unsigned short*)(base);                        // 2 MB
  unsigned short* xoutA = (unsigned short*)(base + (2u << 20));           // 4 MB
  unsigned short* xoutB = (unsigned short*)(base + (6u << 20));           // 4 MB
  unsigned short* xgP   = (unsigned short*)(base + (10u << 20));          // 16 MB
  unsigned*       wfrag = (unsigned*)(base + (26u << 20));                // 512 KB
  float*          biasP = (float*)(base + (26u << 20) + (512u << 10));    // 8 KB

  embed_bf16<<<ROWS, 256, 0, stream>>>(input_ids, embedding, x0);

  const unsigned short* cur = x0;
  unsigned short* nxt = xoutA;
  for (int l = 0; l < 4; ++l) {
    int K = l ? 512 : 256;
    const float* wih = l ? (w_ih_rest + (size_t)(l - 1) * 2 * 1024 * 512) : w_ih_l0;
    pack_whh_mx<<<dim3(64, 2, 2), 64, 0, stream>>>(
        w_hh + (size_t)l * 2 * 1024 * 256, wfrag);
    bias_perm<<<8, 256, 0, stream>>>(bvec + (size_t)l * 4096, biasP);
    gemm_xg_bf16<<<dim3(16, 64, 2), 256, 0, stream>>>(cur, K, wih, biasP, xgP);
    lstm_mx<<<8, 512, 0, stream>>>(xgP, wfrag, nxt);
    cur = nxt;
    nxt = (nxt == xoutA) ? xoutB : xoutA;
  }

  ln_logits<<<ROWS, 64, 0, stream>>>(cur, ln_g, ln_b, lin_w, lin_b, out);
  crf_kernel<<<1, 256, 0, stream>>>(out, labels, attn_mask, crf_start, crf_end,
                                    crf_trans, out + (size_t)ROWS * LL);
}

// Round 7
// 1215.945 us; speedup vs baseline: 8.6167x; 1.0463x over previous
//
#include <hip/hip_runtime.h>
#include <math.h>

// Problem constants: B=16, S=256, E=256, H=256, V=50000, L=9
#define BB 16
#define SS 256
#define LL 9
#define ROWS 4096
#define APITCH 40      // bf16 elems per LDS row in GEMM (80 B)
#define HP 272         // bytes per batch row of H in LDS (fp8): conflict-free b128

typedef __attribute__((ext_vector_type(8))) short short8;   // 8 bf16
typedef __attribute__((ext_vector_type(4))) float f32x4;    // MFMA acc
typedef __attribute__((ext_vector_type(8))) int i32x8;      // 32B MX fragment

#define HSCALE 256.0f
#define LOG2E  1.44269504f
// per-gate weight pack constants: i,f,o = -LOG2E*1024; g = +2*LOG2E*512
// (both magnitudes = 1477.32); dequant scales: 2^-18 (0x6D) and 2^-17 (0x6E)
#define WCONST 1477.3199f
#define SCALE_ONE 0x7F7F7F7Fu
#define SCALE_IFO 0x6D6D6D6Du
#define SCALE_G   0x6E6E6E6Eu

__device__ __forceinline__ unsigned short f2bf(float f) {
  unsigned u = __float_as_uint(f);
  return (unsigned short)((u + 0x7FFF + ((u >> 16) & 1)) >> 16);  // RNE
}
__device__ __forceinline__ float bf2f(unsigned short s) {
  return __uint_as_float(((unsigned)s) << 16);
}

// ---------------------------------------------------------------------------
// Embedding gather -> bf16 x0 [4096][256]
__global__ __launch_bounds__(256) void embed_bf16(
    const int* __restrict__ ids, const float* __restrict__ emb,
    unsigned short* __restrict__ x0) {
  int row = blockIdx.x;
  int id = ids[row];
  x0[(size_t)row * 256 + threadIdx.x] = f2bf(emb[(size_t)id * 256 + threadIdx.x]);
}

// ---------------------------------------------------------------------------
// Pack w_hh (ALL layers) into fp8 e4m3 MX B-fragments (K=128) with the
// log-domain constants folded in: gates i,f,o scaled by -LOG2E*1024,
// gate g by +2*LOG2E*512.
__global__ __launch_bounds__(64) void pack_whh_mx(
    const float* __restrict__ w, unsigned* __restrict__ wfrag) {
  int nb = blockIdx.x, ks2 = blockIdx.y, z = blockIdx.z;  // z = layer*2+dir
  int lane = threadIdx.x, qq = lane >> 4, col = lane & 15;
  int g = nb >> 4;
  float csc = (g == 2) ? WCONST : -WCONST;
  const float* wp = w + (size_t)z * 1024 * 256 + (size_t)(nb * 16 + col) * 256 +
                    ks2 * 128 + qq * 32;
  unsigned* op = wfrag + (((size_t)(z * 64 + nb) * 2 + ks2) * 64 + lane) * 8;
#pragma unroll
  for (int u = 0; u < 8; ++u) {
    float v0 = wp[u * 4 + 0] * csc, v1 = wp[u * 4 + 1] * csc;
    float v2 = wp[u * 4 + 2] * csc, v3 = wp[u * 4 + 3] * csc;
    unsigned pk = __builtin_amdgcn_cvt_pk_fp8_f32(v0, v1, 0, false);
    pk = __builtin_amdgcn_cvt_pk_fp8_f32(v2, v3, pk, true);
    op[u] = pk;
  }
}

// ---------------------------------------------------------------------------
// biasP[l][dir][n'] = b_ih[n] + b_hh[n],  n' = j*4+g, n = g*256+j  (all layers)
__global__ __launch_bounds__(256) void bias_perm(
    const float* __restrict__ b2, float* __restrict__ biasP) {
  int i = blockIdx.x * 256 + threadIdx.x;  // 0..8191
  int l = i >> 11, r = i & 2047;
  int dir = r >> 10, np = r & 1023;
  int n = ((np & 3) << 8) + (np >> 2);
  biasP[i] = b2[l * 4096 + dir * 2048 + n] + b2[l * 4096 + dir * 2048 + 1024 + n];
}

// ---------------------------------------------------------------------------
// bf16 MFMA GEMM: xgP[dir][row][n'] = (sum_k A[row][k]*Wih[dir][n(n')][k] + b)*cg
// cg = -LOG2E for gates i,f,o and +2*LOG2E for gate g (log-domain epilogue).
__global__ __launch_bounds__(256) void gemm_xg_bf16(
    const unsigned short* __restrict__ A, int K,
    const float* __restrict__ Wih,
    const float* __restrict__ biasP,
    unsigned short* __restrict__ xgP) {
  int dir = blockIdx.z;
  const float* Bw = Wih + (size_t)dir * 1024 * K;
  int n0 = blockIdx.x * 64, m0 = blockIdx.y * 64;
  int tid = threadIdx.x;
  int wv = tid >> 6, lane = tid & 63, quad = lane >> 4, col = lane & 15;
  __shared__ unsigned short As[64 * APITCH];
  __shared__ unsigned short Bs[64 * APITCH];
  int lr = tid >> 2;
  int lk = (tid & 3) * 8;
  int nprime = n0 + lr;
  int nphys = ((nprime & 3) << 8) + (nprime >> 2);
  f32x4 acc[4];
#pragma unroll
  for (int nt = 0; nt < 4; ++nt) acc[nt] = (f32x4){0.f, 0.f, 0.f, 0.f};

  for (int k0 = 0; k0 < K; k0 += 32) {
    short8 av = *(const short8*)&A[(size_t)(m0 + lr) * K + k0 + lk];
    float4 b0 = *(const float4*)&Bw[(size_t)nphys * K + k0 + lk];
    float4 b1 = *(const float4*)&Bw[(size_t)nphys * K + k0 + lk + 4];
    short8 bv;
    bv[0] = (short)f2bf(b0.x); bv[1] = (short)f2bf(b0.y);
    bv[2] = (short)f2bf(b0.z); bv[3] = (short)f2bf(b0.w);
    bv[4] = (short)f2bf(b1.x); bv[5] = (short)f2bf(b1.y);
    bv[6] = (short)f2bf(b1.z); bv[7] = (short)f2bf(b1.w);
    __syncthreads();
    *(short8*)&As[lr * APITCH + lk] = av;
    *(short8*)&Bs[lr * APITCH + lk] = bv;
    __syncthreads();
    short8 af = *(const short8*)&As[(wv * 16 + col) * APITCH + quad * 8];
#pragma unroll
    for (int nt = 0; nt < 4; ++nt) {
      short8 bf = *(const short8*)&Bs[(nt * 16 + col) * APITCH + quad * 8];
      acc[nt] = __builtin_amdgcn_mfma_f32_16x16x32_bf16(af, bf, acc[nt], 0, 0, 0);
    }
  }
#pragma unroll
  for (int nt = 0; nt < 4; ++nt) {
    int np = n0 + nt * 16 + col;
    float bia = biasP[dir * 1024 + np];
    float cg = ((np & 3) == 2) ? (2.0f * LOG2E) : (-LOG2E);
#pragma unroll
    for (int r = 0; r < 4; ++r) {
      int row = m0 + wv * 16 + quad * 4 + r;
      xgP[((size_t)dir * ROWS + row) * 1024 + np] = f2bf((acc[nt][r] + bia) * cg);
    }
  }
}

// ---------------------------------------------------------------------------
// MX-fp8 (K=128) MFMA LSTM recurrence. grid = 16 blocks (bg*2+dir), 2 batches
// per block, 512 threads (8 waves, 2/SIMD). A-operand batch-replicated 8x in M
// (lane reads H[(lane&15)>>3]) -> every lane owns exactly ONE cell:
// (b = bg*2 + (quad>>1), j = 32*wv + 16*(quad&1) + col), all 4 gates in acc
// reg 0 of the hbi=(quad&1) tiles. Log-domain gates: weights & xg pre-scaled
// by -LOG2E (i,f,o) / +2LOG2E (g); cell state kept as C' = 2*LOG2E*c.
// Epilogue: 4 exp2 + 4 rcp + ~20 VALU, no muls before exp2, no divisions.
__global__ __launch_bounds__(512, 2) void lstm_mx(
    const unsigned short* __restrict__ xgP,   // [2][4096][1024] bf16 n'=j*4+g
    const unsigned* __restrict__ wfrag,       // layer slice: [2][64][2][64][8] dw
    unsigned short* __restrict__ xout) {      // [4096][512] bf16
  int dir = blockIdx.x & 1;
  int bg = blockIdx.x >> 1;            // 0..7 -> batches bg*2, bg*2+1
  int tid = threadIdx.x;
  int wv = tid >> 6, lane = tid & 63;
  int quad = lane >> 4, col = lane & 15;

  __shared__ __align__(16) unsigned char Hfrag[2][2 * HP];

  {  // zero both H buffers (2*2*HP bytes = HP ints)
    int* hz = (int*)&Hfrag[0][0];
    for (int i = tid; i < HP; i += 512) hz[i] = 0;
  }

  // weight fragments, loaded once: wf[hbi][g][ks2] (128 regs -> AGPRs)
  i32x8 wf[2][4][2];
#pragma unroll
  for (int hbi = 0; hbi < 2; ++hbi)
#pragma unroll
    for (int g = 0; g < 4; ++g) {
      int nb = g * 16 + 2 * wv + hbi;
#pragma unroll
      for (int ks2 = 0; ks2 < 2; ++ks2)
        wf[hbi][g][ks2] = *(const i32x8*)(wfrag +
            (((size_t)(dir * 64 + nb) * 2 + ks2) * 64 + lane) * 8);
    }

  // batch-replicated A-read offset: lane reads H[(lane&15)>>3]
  int aoff = ((lane & 15) >> 3) * HP + (lane >> 4) * 32;

  int hbsel = quad & 1;
  int bq = quad >> 1;
  int j = 32 * wv + 16 * hbsel + col;
  int b = bg * 2 + bq;
  int pos0 = dir ? (SS - 1) : 0;
  int dstep = dir ? -1 : 1;
  const unsigned short* xq_ptr =
      xgP + ((size_t)dir * ROWS + (size_t)b * SS + pos0) * 1024 + j * 4;
  unsigned short* xo_ptr = xout + ((size_t)b * SS + pos0) * 512 + dir * 256 + j;
  int xq_d = dstep * 1024;
  int xo_d = dstep * 512;
  int hw = bq * HP + j;

  float Cp = 0.f;                 // C' = 2*LOG2E * c
  unsigned short ph = 0;
  unsigned short* xo_prev = xo_ptr;
  int cur = 0;
  __syncthreads();

  for (int t = 0; t < SS; ++t) {
    // deferred xout store from previous step (drains under MFMA phase)
    if (t) *xo_prev = ph;
    ushort4 xq = *(const ushort4*)xq_ptr;
    xq_ptr += xq_d;

    // ---- MFMA phase (A batch-replicated; broadcast + conflict-free reads)
    i32x8 af0 = *(const i32x8*)&Hfrag[cur][aoff];
    i32x8 af1 = *(const i32x8*)&Hfrag[cur][aoff + 128];
    f32x4 acc[2][4];
#pragma unroll
    for (int hbi = 0; hbi < 2; ++hbi) {
#pragma unroll
      for (int g = 0; g < 4; ++g) {
        f32x4 a = (f32x4){0.f, 0.f, 0.f, 0.f};
        a = __builtin_amdgcn_mfma_scale_f32_16x16x128_f8f6f4(
                af0, wf[hbi][g][0], a, 0, 0, 0, SCALE_ONE, 0,
                (g == 2) ? SCALE_G : SCALE_IFO);
        a = __builtin_amdgcn_mfma_scale_f32_16x16x128_f8f6f4(
                af1, wf[hbi][g][1], a, 0, 0, 0, SCALE_ONE, 0,
                (g == 2) ? SCALE_G : SCALE_IFO);
        acc[hbi][g] = a;
      }
    }

    // ---- in-register epilogue: one cell per lane, log-domain gates
    int nxt = cur ^ 1;
    float a_i = hbsel ? acc[1][0][0] : acc[0][0][0];
    float a_f = hbsel ? acc[1][1][0] : acc[0][1][0];
    float a_g = hbsel ? acc[1][2][0] : acc[0][2][0];
    float a_o = hbsel ? acc[1][3][0] : acc[0][3][0];
    float gi = a_i + bf2f(xq.x);   // = -LOG2E * (raw i-gate)
    float gf = a_f + bf2f(xq.y);
    float gt = a_g + bf2f(xq.z);   // = 2*LOG2E * (raw g-gate)
    float go = a_o + bf2f(xq.w);
    float si = __builtin_amdgcn_rcpf(1.0f + __builtin_amdgcn_exp2f(gi));
    float sf = __builtin_amdgcn_rcpf(1.0f + __builtin_amdgcn_exp2f(gf));
    float so = __builtin_amdgcn_rcpf(1.0f + __builtin_amdgcn_exp2f(go));
    float rg = __builtin_amdgcn_rcpf(1.0f + __builtin_amdgcn_exp2f(gt));
    float tg2 = fmaf(-4.0f * LOG2E, rg, 2.0f * LOG2E);  // 2LOG2E*tanh(g)
    Cp = fmaf(sf, Cp, si * tg2);
    float rc = __builtin_amdgcn_rcpf(1.0f + __builtin_amdgcn_exp2f(Cp));
    float h = so * fmaf(-2.0f, rc, 1.0f);
    unsigned pk = __builtin_amdgcn_cvt_pk_fp8_f32(h * HSCALE, h * HSCALE, 0, false);
    Hfrag[nxt][hw] = (unsigned char)(pk & 0xFF);
    ph = f2bf(h);
    xo_prev = xo_ptr;
    xo_ptr += xo_d;
    __syncthreads();
    cur = nxt;
  }
  *xo_prev = ph;
}

// ---------------------------------------------------------------------------
// LayerNorm + 9-way linear. One wave per row. X is bf16 [4096][512].
__global__ __launch_bounds__(64) void ln_logits(
    const unsigned short* __restrict__ X, const float* __restrict__ g,
    const float* __restrict__ bt, const float* __restrict__ W,
    const float* __restrict__ lb, float* __restrict__ out) {
  int row = blockIdx.x;
  int lane = threadIdx.x;
  const unsigned short* x = X + (size_t)row * 512;
  float v[8];
  float s = 0.f, s2 = 0.f;
#pragma unroll
  for (int i = 0; i < 8; ++i) {
    v[i] = bf2f(x[lane + 64 * i]);
    s += v[i];
    s2 += v[i] * v[i];
  }
#pragma unroll
  for (int off = 32; off; off >>= 1) {
    s += __shfl_down(s, off, 64);
    s2 += __shfl_down(s2, off, 64);
  }
  s = __shfl(s, 0, 64);
  s2 = __shfl(s2, 0, 64);
  float mu = s * (1.f / 512.f);
  float var = s2 * (1.f / 512.f) - mu * mu;
  float rstd = rsqrtf(var + 1e-5f);
  float y[8];
#pragma unroll
  for (int i = 0; i < 8; ++i) {
    int e = lane + 64 * i;
    y[i] = (v[i] - mu) * rstd * g[e] + bt[e];
  }
  for (int l = 0; l < LL; ++l) {
    float p = 0.f;
#pragma unroll
    for (int i = 0; i < 8; ++i) p += y[i] * W[(size_t)l * 512 + lane + 64 * i];
#pragma unroll
    for (int off = 32; off; off >>= 1) p += __shfl_down(p, off, 64);
    if (lane == 0) out[(size_t)row * LL + l] = p + lb[l];
  }
}

// ---------------------------------------------------------------------------
// CRF numerator + denominator + loss. One block of 256 threads.
__global__ __launch_bounds__(256) void crf_kernel(
    const float* __restrict__ logits, const int* __restrict__ labels,
    const int* __restrict__ mask, const float* __restrict__ cs,
    const float* __restrict__ ce, const float* __restrict__ ct,
    float* __restrict__ loss_out) {
  __shared__ float trans[9][12];
  __shared__ float alpha[2][BB][12];
  __shared__ float numsh[BB];
  __shared__ float res[BB];
  int tid = threadIdx.x;
  int b = tid >> 4;
  int i = tid & 15;
  if (tid < 81) trans[tid / 9][tid % 9] = ct[tid];
  __syncthreads();
  const float* lg = logits + (size_t)b * SS * LL;
  const int* lbp = labels + (size_t)b * SS;
  const int* mk = mask + (size_t)b * SS;

  float np = 0.f;
  int msum = 0;
  for (int t = i; t < SS; t += 16) {
    msum += mk[t];
    if (t == 0) {
      int l0 = lbp[0];
      np += cs[l0] + lg[l0];
    } else {
      float m = (float)mk[t];
      np += (trans[lbp[t - 1]][lbp[t]] + lg[(size_t)t * LL + lbp[t]]) * m;
    }
  }
#pragma unroll
  for (int off = 8; off; off >>= 1) {
    np += __shfl_down(np, off, 16);
    msum += __shfl_down(msum, off, 16);
  }
  if (i == 0) {
    int last = msum - 1;
    numsh[b] = np + ce[lbp[last]];
  }

  if (i < LL) alpha[0][b][i] = cs[i] + lg[i];
  int cur = 0;
  for (int t = 1; t < SS; ++t) {
    if (i < LL) {
      float e = lg[(size_t)t * LL + i];
      float av[9];
      float mmax = -1e30f;
#pragma unroll
      for (int p = 0; p < LL; ++p) {
        float vv = alpha[cur][b][p] + trans[p][i];
        av[p] = vv;
        mmax = fmaxf(mmax, vv);
      }
      float ssum = 0.f;
#pragma unroll
      for (int p = 0; p < LL; ++p) ssum += __expf(av[p] - mmax);
      float anew = e + mmax + logf(ssum);
      float aold = alpha[cur][b][i];
      alpha[cur ^ 1][b][i] = (mk[t] > 0) ? anew : aold;
    }
    cur ^= 1;
  }
  if (i == 0) {
    float arr[9];
    float m2 = -1e30f;
#pragma unroll
    for (int cc = 0; cc < LL; ++cc) {
      arr[cc] = alpha[cur][b][cc] + ce[cc];
      m2 = fmaxf(m2, arr[cc]);
    }
    float ssd = 0.f;
#pragma unroll
    for (int cc = 0; cc < LL; ++cc) ssd += __expf(arr[cc] - m2);
    float denom = m2 + logf(ssd);
    res[b] = numsh[b] - denom;
  }
  __syncthreads();
  if (tid == 0) {
    float Lsum = 0.f;
    for (int b2 = 0; b2 < BB; ++b2) Lsum += res[b2];
    loss_out[0] = -Lsum;
  }
}

// ---------------------------------------------------------------------------
extern "C" void kernel_launch(void* const* d_in, const int* in_sizes, int n_in,
                              void* d_out, int out_size, void* d_ws, size_t ws_size,
                              hipStream_t stream) {
  const int* input_ids = (const int*)d_in[0];
  const int* attn_mask = (const int*)d_in[1];
  const int* labels = (const int*)d_in[2];
  const float* embedding = (const float*)d_in[3];
  const float* w_ih_l0 = (const float*)d_in[4];
  const float* w_ih_rest = (const float*)d_in[5];
  const float* w_hh = (const float*)d_in[6];
  const float* bvec = (const float*)d_in[7];
  const float* ln_g = (const float*)d_in[8];
  const float* ln_b = (const float*)d_in[9];
  const float* lin_w = (const float*)d_in[10];
  const float* lin_b = (const float*)d_in[11];
  const float* crf_start = (const float*)d_in[12];
  const float* crf_end = (const float*)d_in[13];
  const float* crf_trans = (const float*)d_in[14];
  float* out = (float*)d_out;
  char* base = (char*)d_ws;

  unsigned short* x0    = (unsigned short*)(base);                        // 2 MB
  unsigned short* xoutA = (unsigned short*)(base + (2u << 20));           // 4 MB
  unsigned short* xoutB = (unsigned short*)(base + (6u << 20));           // 4 MB
  unsigned short* xgP   = (unsigned short*)(base + (10u << 20));          // 16 MB
  unsigned*       wfrag = (unsigned*)(base + (26u << 20));                // 2 MB (4 layers)
  float*          biasP = (float*)(base + (28u << 20));                   // 32 KB

  embed_bf16<<<ROWS, 256, 0, stream>>>(input_ids, embedding, x0);
  pack_whh_mx<<<dim3(64, 2, 8), 64, 0, stream>>>(w_hh, wfrag);
  bias_perm<<<32, 256, 0, stream>>>(bvec, biasP);

  const unsigned short* cur = x0;
  unsigned short* nxt = xoutA;
  for (int l = 0; l < 4; ++l) {
    int K = l ? 512 : 256;
    const float* wih = l ? (w_ih_rest + (size_t)(l - 1) * 2 * 1024 * 512) : w_ih_l0;
    gemm_xg_bf16<<<dim3(16, 64, 2), 256, 0, stream>>>(
        cur, K, wih, biasP + (size_t)l * 2048, xgP);
    lstm_mx<<<16, 512, 0, stream>>>(xgP, wfrag + (size_t)l * 131072, nxt);
    cur = nxt;
    nxt = (nxt == xoutA) ? xoutB : xoutA;
  }

  ln_logits<<<ROWS, 64, 0, stream>>>(cur, ln_g, ln_b, lin_w, lin_b, out);
  crf_kernel<<<1, 256, 0, stream>>>(out, labels, attn_mask, crf_start, crf_end,
                                    crf_trans, out + (size_t)ROWS * LL);
}

// Round 8
// 1198.487 us; speedup vs baseline: 8.7423x; 1.0146x over previous
//
#include <hip/hip_runtime.h>
#include <math.h>
#include <stdint.h>

// Problem constants: B=16, S=256, E=256, H=256, V=50000, L=9
#define BB 16
#define SS 256
#define LL 9
#define ROWS 4096
#define HP 272         // bytes per batch row of H in LDS (fp8)

typedef __attribute__((ext_vector_type(8))) short short8;   // 8 bf16
typedef __attribute__((ext_vector_type(4))) float f32x4;    // MFMA acc
typedef __attribute__((ext_vector_type(8))) int i32x8;      // 32B MX fragment

#define HSCALE 256.0f
#define LOG2E  1.44269504f
// per-gate weight pack constants: i,f,o = -LOG2E*1024; g = +2*LOG2E*512
#define WCONST 1477.3199f
#define SCALE_ONE 0x7F7F7F7Fu
#define SCALE_IFO 0x6D6D6D6Du
#define SCALE_G   0x6E6E6E6Eu

__device__ __forceinline__ unsigned short f2bf(float f) {
  unsigned u = __float_as_uint(f);
  return (unsigned short)((u + 0x7FFF + ((u >> 16) & 1)) >> 16);  // RNE
}
__device__ __forceinline__ float bf2f(unsigned short s) {
  return __uint_as_float(((unsigned)s) << 16);
}

// async global->LDS, 16B per lane; LDS dest = (wave-uniform base) + lane*16
__device__ __forceinline__ void gl2lds16(const void* g, void* l) {
  __builtin_amdgcn_global_load_lds(
      (const __attribute__((address_space(1))) void*)g,
      (__attribute__((address_space(3))) void*)l, 16, 0, 0);
}

// ---------------------------------------------------------------------------
// Embedding gather -> bf16 x0 [4096][256]
__global__ __launch_bounds__(256) void embed_bf16(
    const int* __restrict__ ids, const float* __restrict__ emb,
    unsigned short* __restrict__ x0) {
  int row = blockIdx.x;
  int id = ids[row];
  x0[(size_t)row * 256 + threadIdx.x] = f2bf(emb[(size_t)id * 256 + threadIdx.x]);
}

// ---------------------------------------------------------------------------
// Pack w_hh (ALL layers) into fp8 e4m3 MX B-fragments (K=128), log-domain consts.
__global__ __launch_bounds__(64) void pack_whh_mx(
    const float* __restrict__ w, unsigned* __restrict__ wfrag) {
  int nb = blockIdx.x, ks2 = blockIdx.y, z = blockIdx.z;  // z = layer*2+dir
  int lane = threadIdx.x, qq = lane >> 4, col = lane & 15;
  int g = nb >> 4;
  float csc = (g == 2) ? WCONST : -WCONST;
  const float* wp = w + (size_t)z * 1024 * 256 + (size_t)(nb * 16 + col) * 256 +
                    ks2 * 128 + qq * 32;
  unsigned* op = wfrag + (((size_t)(z * 64 + nb) * 2 + ks2) * 64 + lane) * 8;
#pragma unroll
  for (int u = 0; u < 8; ++u) {
    float v0 = wp[u * 4 + 0] * csc, v1 = wp[u * 4 + 1] * csc;
    float v2 = wp[u * 4 + 2] * csc, v3 = wp[u * 4 + 3] * csc;
    unsigned pk = __builtin_amdgcn_cvt_pk_fp8_f32(v0, v1, 0, false);
    pk = __builtin_amdgcn_cvt_pk_fp8_f32(v2, v3, pk, true);
    op[u] = pk;
  }
}

// ---------------------------------------------------------------------------
// biasPF[l][dir][n'] = (b_ih[n]+b_hh[n]) * cg(n'),  n' = j*4+g, n = g*256+j
__global__ __launch_bounds__(256) void bias_perm(
    const float* __restrict__ b2, float* __restrict__ biasPF) {
  int i = blockIdx.x * 256 + threadIdx.x;  // 0..8191
  int l = i >> 11, r = i & 2047;
  int dir = r >> 10, np = r & 1023;
  int n = ((np & 3) << 8) + (np >> 2);
  float cg = ((np & 3) == 2) ? (2.0f * LOG2E) : (-LOG2E);
  biasPF[i] = (b2[l * 4096 + dir * 2048 + n] + b2[l * 4096 + dir * 2048 + 1024 + n]) * cg;
}

// ---------------------------------------------------------------------------
// Pre-convert W_ih (all layers) to bf16, gate-permuted rows, cg folded:
// wp[l][dir][n'][k] = bf16( W[l][dir][nphys(n')][k] * cg(n') )
__global__ __launch_bounds__(256) void prep_wih(
    const float* __restrict__ w_l0, const float* __restrict__ w_rest,
    unsigned short* __restrict__ wp, const long* __restrict__ woff_dummy) {
  int l = blockIdx.z;
  int Ksh = l ? 9 : 8;
  int K = 1 << Ksh;
  long total = (long)2 * 1024 * K;
  long idx = (long)blockIdx.x * 256 + threadIdx.x;
  if (idx >= total) return;
  int k = (int)(idx & (K - 1));
  long r = idx >> Ksh;
  int np = (int)(r & 1023), dir = (int)(r >> 10);
  int nph = ((np & 3) << 8) + (np >> 2);
  float cg = ((np & 3) == 2) ? (2.0f * LOG2E) : (-LOG2E);
  const float* src = l ? (w_rest + (size_t)(l - 1) * 2 * 1024 * 512) : w_l0;
  size_t off = l ? (524288 + (size_t)(l - 1) * 1048576) : 0;
  wp[off + idx] = f2bf(src[((size_t)dir * 1024 + nph) * K + k] * cg);
}

// ---------------------------------------------------------------------------
// m97-style bf16 MFMA GEMM with global_load_lds staging.
// xgP[dir][row][n'] = sum_k A[row][k]*BP[dir][n'][k] + biasPF  (cg pre-folded)
// Block 512 thr (8 waves), tile M128 x N128, BK=32, 2 blocks/CU.
__global__ __launch_bounds__(512) void gemm_xg128(
    const unsigned short* __restrict__ A, int K,
    const unsigned short* __restrict__ BP,
    const float* __restrict__ biasPF,
    unsigned short* __restrict__ xgP) {
  int dir = blockIdx.z;
  int n0 = blockIdx.x * 128, m0 = blockIdx.y * 128;
  int tid = threadIdx.x;
  int wv = tid >> 6, lane = tid & 63, quad = lane >> 4, col = lane & 15;
  __shared__ unsigned short As[128 * 32];
  __shared__ unsigned short Bs[128 * 32];
  const unsigned short* Bw = BP + (size_t)dir * 1024 * K;

  // staging: wave wv stages rows [16wv,16wv+16) of A and B; lane -> (row,kc)
  int srow = lane >> 2;
  int scol = (lane & 3) * 8;
  const unsigned short* ga = A + (size_t)(m0 + wv * 16 + srow) * K + scol;
  const unsigned short* gb = Bw + (size_t)(n0 + wv * 16 + srow) * K + scol;
  unsigned short* lA = &As[wv * 512];   // 1 KB per wave slice
  unsigned short* lB = &Bs[wv * 512];

  int wm = wv & 1;       // M 64-half
  int wn = wv >> 1;      // N 32-slice
  f32x4 acc[4][2];
#pragma unroll
  for (int mt = 0; mt < 4; ++mt)
#pragma unroll
    for (int nt = 0; nt < 2; ++nt) acc[mt][nt] = (f32x4){0.f, 0.f, 0.f, 0.f};

  for (int k0 = 0; k0 < K; k0 += 32) {
    __syncthreads();               // prior iteration's fragment reads done
    gl2lds16(ga, lA);
    gl2lds16(gb, lB);
    ga += 32; gb += 32;
    __syncthreads();               // drains vmcnt -> LDS data visible
    short8 bf0 = *(const short8*)&Bs[(wn * 32 + col) * 32 + quad * 8];
    short8 bf1 = *(const short8*)&Bs[(wn * 32 + 16 + col) * 32 + quad * 8];
#pragma unroll
    for (int mt = 0; mt < 4; ++mt) {
      short8 af = *(const short8*)&As[(wm * 64 + mt * 16 + col) * 32 + quad * 8];
      acc[mt][0] = __builtin_amdgcn_mfma_f32_16x16x32_bf16(af, bf0, acc[mt][0], 0, 0, 0);
      acc[mt][1] = __builtin_amdgcn_mfma_f32_16x16x32_bf16(af, bf1, acc[mt][1], 0, 0, 0);
    }
  }

#pragma unroll
  for (int nt = 0; nt < 2; ++nt) {
    int np = n0 + wn * 32 + nt * 16 + col;
    float bia = biasPF[dir * 1024 + np];
#pragma unroll
    for (int mt = 0; mt < 4; ++mt) {
#pragma unroll
      for (int r = 0; r < 4; ++r) {
        int row = m0 + wm * 64 + mt * 16 + quad * 4 + r;
        xgP[((size_t)dir * ROWS + row) * 1024 + np] = f2bf(acc[mt][nt][r] + bia);
      }
    }
  }
}

// ---------------------------------------------------------------------------
// MX-fp8 (K=128) MFMA LSTM recurrence (unchanged from round 7).
__global__ __launch_bounds__(512, 2) void lstm_mx(
    const unsigned short* __restrict__ xgP,   // [2][4096][1024] bf16 n'=j*4+g
    const unsigned* __restrict__ wfrag,       // layer slice: [2][64][2][64][8] dw
    unsigned short* __restrict__ xout) {      // [4096][512] bf16
  int dir = blockIdx.x & 1;
  int bg = blockIdx.x >> 1;            // 0..7 -> batches bg*2, bg*2+1
  int tid = threadIdx.x;
  int wv = tid >> 6, lane = tid & 63;
  int quad = lane >> 4, col = lane & 15;

  __shared__ __align__(16) unsigned char Hfrag[2][2 * HP];

  {
    int* hz = (int*)&Hfrag[0][0];
    for (int i = tid; i < HP; i += 512) hz[i] = 0;
  }

  i32x8 wf[2][4][2];
#pragma unroll
  for (int hbi = 0; hbi < 2; ++hbi)
#pragma unroll
    for (int g = 0; g < 4; ++g) {
      int nb = g * 16 + 2 * wv + hbi;
#pragma unroll
      for (int ks2 = 0; ks2 < 2; ++ks2)
        wf[hbi][g][ks2] = *(const i32x8*)(wfrag +
            (((size_t)(dir * 64 + nb) * 2 + ks2) * 64 + lane) * 8);
    }

  int aoff = ((lane & 15) >> 3) * HP + (lane >> 4) * 32;

  int hbsel = quad & 1;
  int bq = quad >> 1;
  int j = 32 * wv + 16 * hbsel + col;
  int b = bg * 2 + bq;
  int pos0 = dir ? (SS - 1) : 0;
  int dstep = dir ? -1 : 1;
  const unsigned short* xq_ptr =
      xgP + ((size_t)dir * ROWS + (size_t)b * SS + pos0) * 1024 + j * 4;
  unsigned short* xo_ptr = xout + ((size_t)b * SS + pos0) * 512 + dir * 256 + j;
  int xq_d = dstep * 1024;
  int xo_d = dstep * 512;
  int hw = bq * HP + j;

  float Cp = 0.f;                 // C' = 2*LOG2E * c
  unsigned short ph = 0;
  unsigned short* xo_prev = xo_ptr;
  int cur = 0;
  __syncthreads();

  for (int t = 0; t < SS; ++t) {
    if (t) *xo_prev = ph;
    ushort4 xq = *(const ushort4*)xq_ptr;
    xq_ptr += xq_d;

    i32x8 af0 = *(const i32x8*)&Hfrag[cur][aoff];
    i32x8 af1 = *(const i32x8*)&Hfrag[cur][aoff + 128];
    f32x4 acc[2][4];
#pragma unroll
    for (int hbi = 0; hbi < 2; ++hbi) {
#pragma unroll
      for (int g = 0; g < 4; ++g) {
        f32x4 a = (f32x4){0.f, 0.f, 0.f, 0.f};
        a = __builtin_amdgcn_mfma_scale_f32_16x16x128_f8f6f4(
                af0, wf[hbi][g][0], a, 0, 0, 0, SCALE_ONE, 0,
                (g == 2) ? SCALE_G : SCALE_IFO);
        a = __builtin_amdgcn_mfma_scale_f32_16x16x128_f8f6f4(
                af1, wf[hbi][g][1], a, 0, 0, 0, SCALE_ONE, 0,
                (g == 2) ? SCALE_G : SCALE_IFO);
        acc[hbi][g] = a;
      }
    }

    int nxt = cur ^ 1;
    float a_i = hbsel ? acc[1][0][0] : acc[0][0][0];
    float a_f = hbsel ? acc[1][1][0] : acc[0][1][0];
    float a_g = hbsel ? acc[1][2][0] : acc[0][2][0];
    float a_o = hbsel ? acc[1][3][0] : acc[0][3][0];
    float gi = a_i + bf2f(xq.x);
    float gf = a_f + bf2f(xq.y);
    float gt = a_g + bf2f(xq.z);
    float go = a_o + bf2f(xq.w);
    float si = __builtin_amdgcn_rcpf(1.0f + __builtin_amdgcn_exp2f(gi));
    float sf = __builtin_amdgcn_rcpf(1.0f + __builtin_amdgcn_exp2f(gf));
    float so = __builtin_amdgcn_rcpf(1.0f + __builtin_amdgcn_exp2f(go));
    float rg = __builtin_amdgcn_rcpf(1.0f + __builtin_amdgcn_exp2f(gt));
    float tg2 = fmaf(-4.0f * LOG2E, rg, 2.0f * LOG2E);
    Cp = fmaf(sf, Cp, si * tg2);
    float rc = __builtin_amdgcn_rcpf(1.0f + __builtin_amdgcn_exp2f(Cp));
    float h = so * fmaf(-2.0f, rc, 1.0f);
    unsigned pk = __builtin_amdgcn_cvt_pk_fp8_f32(h * HSCALE, h * HSCALE, 0, false);
    Hfrag[nxt][hw] = (unsigned char)(pk & 0xFF);
    ph = f2bf(h);
    xo_prev = xo_ptr;
    xo_ptr += xo_d;
    __syncthreads();
    cur = nxt;
  }
  *xo_prev = ph;
}

// ---------------------------------------------------------------------------
// LayerNorm + 9-way linear. One wave per row. X is bf16 [4096][512].
__global__ __launch_bounds__(64) void ln_logits(
    const unsigned short* __restrict__ X, const float* __restrict__ g,
    const float* __restrict__ bt, const float* __restrict__ W,
    const float* __restrict__ lb, float* __restrict__ out) {
  int row = blockIdx.x;
  int lane = threadIdx.x;
  const unsigned short* x = X + (size_t)row * 512;
  float v[8];
  float s = 0.f, s2 = 0.f;
#pragma unroll
  for (int i = 0; i < 8; ++i) {
    v[i] = bf2f(x[lane + 64 * i]);
    s += v[i];
    s2 += v[i] * v[i];
  }
#pragma unroll
  for (int off = 32; off; off >>= 1) {
    s += __shfl_down(s, off, 64);
    s2 += __shfl_down(s2, off, 64);
  }
  s = __shfl(s, 0, 64);
  s2 = __shfl(s2, 0, 64);
  float mu = s * (1.f / 512.f);
  float var = s2 * (1.f / 512.f) - mu * mu;
  float rstd = rsqrtf(var + 1e-5f);
  float y[8];
#pragma unroll
  for (int i = 0; i < 8; ++i) {
    int e = lane + 64 * i;
    y[i] = (v[i] - mu) * rstd * g[e] + bt[e];
  }
  for (int l = 0; l < LL; ++l) {
    float p = 0.f;
#pragma unroll
    for (int i = 0; i < 8; ++i) p += y[i] * W[(size_t)l * 512 + lane + 64 * i];
#pragma unroll
    for (int off = 32; off; off >>= 1) p += __shfl_down(p, off, 64);
    if (lane == 0) out[(size_t)row * LL + l] = p + lb[l];
  }
}

// ---------------------------------------------------------------------------
// CRF numerator + denominator + loss. One block of 256 threads.
__global__ __launch_bounds__(256) void crf_kernel(
    const float* __restrict__ logits, const int* __restrict__ labels,
    const int* __restrict__ mask, const float* __restrict__ cs,
    const float* __restrict__ ce, const float* __restrict__ ct,
    float* __restrict__ loss_out) {
  __shared__ float trans[9][12];
  __shared__ float alpha[2][BB][12];
  __shared__ float numsh[BB];
  __shared__ float res[BB];
  int tid = threadIdx.x;
  int b = tid >> 4;
  int i = tid & 15;
  if (tid < 81) trans[tid / 9][tid % 9] = ct[tid];
  __syncthreads();
  const float* lg = logits + (size_t)b * SS * LL;
  const int* lbp = labels + (size_t)b * SS;
  const int* mk = mask + (size_t)b * SS;

  float np = 0.f;
  int msum = 0;
  for (int t = i; t < SS; t += 16) {
    msum += mk[t];
    if (t == 0) {
      int l0 = lbp[0];
      np += cs[l0] + lg[l0];
    } else {
      float m = (float)mk[t];
      np += (trans[lbp[t - 1]][lbp[t]] + lg[(size_t)t * LL + lbp[t]]) * m;
    }
  }
#pragma unroll
  for (int off = 8; off; off >>= 1) {
    np += __shfl_down(np, off, 16);
    msum += __shfl_down(msum, off, 16);
  }
  if (i == 0) {
    int last = msum - 1;
    numsh[b] = np + ce[lbp[last]];
  }

  if (i < LL) alpha[0][b][i] = cs[i] + lg[i];
  int cur = 0;
  for (int t = 1; t < SS; ++t) {
    if (i < LL) {
      float e = lg[(size_t)t * LL + i];
      float av[9];
      float mmax = -1e30f;
#pragma unroll
      for (int p = 0; p < LL; ++p) {
        float vv = alpha[cur][b][p] + trans[p][i];
        av[p] = vv;
        mmax = fmaxf(mmax, vv);
      }
      float ssum = 0.f;
#pragma unroll
      for (int p = 0; p < LL; ++p) ssum += __expf(av[p] - mmax);
      float anew = e + mmax + logf(ssum);
      float aold = alpha[cur][b][i];
      alpha[cur ^ 1][b][i] = (mk[t] > 0) ? anew : aold;
    }
    cur ^= 1;
  }
  if (i == 0) {
    float arr[9];
    float m2 = -1e30f;
#pragma unroll
    for (int cc = 0; cc < LL; ++cc) {
      arr[cc] = alpha[cur][b][cc] + ce[cc];
      m2 = fmaxf(m2, arr[cc]);
    }
    float ssd = 0.f;
#pragma unroll
    for (int cc = 0; cc < LL; ++cc) ssd += __expf(arr[cc] - m2);
    float denom = m2 + logf(ssd);
    res[b] = numsh[b] - denom;
  }
  __syncthreads();
  if (tid == 0) {
    float Lsum = 0.f;
    for (int b2 = 0; b2 < BB; ++b2) Lsum += res[b2];
    loss_out[0] = -Lsum;
  }
}

// ---------------------------------------------------------------------------
extern "C" void kernel_launch(void* const* d_in, const int* in_sizes, int n_in,
                              void* d_out, int out_size, void* d_ws, size_t ws_size,
                              hipStream_t stream) {
  const int* input_ids = (const int*)d_in[0];
  const int* attn_mask = (const int*)d_in[1];
  const int* labels = (const int*)d_in[2];
  const float* embedding = (const float*)d_in[3];
  const float* w_ih_l0 = (const float*)d_in[4];
  const float* w_ih_rest = (const float*)d_in[5];
  const float* w_hh = (const float*)d_in[6];
  const float* bvec = (const float*)d_in[7];
  const float* ln_g = (const float*)d_in[8];
  const float* ln_b = (const float*)d_in[9];
  const float* lin_w = (const float*)d_in[10];
  const float* lin_b = (const float*)d_in[11];
  const float* crf_start = (const float*)d_in[12];
  const float* crf_end = (const float*)d_in[13];
  const float* crf_trans = (const float*)d_in[14];
  float* out = (float*)d_out;
  char* base = (char*)d_ws;

  unsigned short* x0    = (unsigned short*)(base);                        // 2 MB
  unsigned short* xoutA = (unsigned short*)(base + (2u << 20));           // 4 MB
  unsigned short* xoutB = (unsigned short*)(base + (6u << 20));           // 4 MB
  unsigned short* xgP   = (unsigned short*)(base + (10u << 20));          // 16 MB
  unsigned*       wfrag = (unsigned*)(base + (26u << 20));                // 2 MB
  float*          biasPF= (float*)(base + (28u << 20));                   // 32 KB
  unsigned short* wihP  = (unsigned short*)(base + (29u << 20));          // 7 MB

  embed_bf16<<<ROWS, 256, 0, stream>>>(input_ids, embedding, x0);
  pack_whh_mx<<<dim3(64, 2, 8), 64, 0, stream>>>(w_hh, wfrag);
  bias_perm<<<32, 256, 0, stream>>>(bvec, biasPF);
  prep_wih<<<dim3(4096, 1, 4), 256, 0, stream>>>(w_ih_l0, w_ih_rest, wihP, nullptr);

  // wihP per-layer offsets (ushorts): l0=0, l1=524288, l2=1572864, l3=2621440
  const size_t WOFF[4] = {0, 524288, 1572864, 2621440};

  const unsigned short* cur = x0;
  unsigned short* nxt = xoutA;
  for (int l = 0; l < 4; ++l) {
    int K = l ? 512 : 256;
    gemm_xg128<<<dim3(8, 32, 2), 512, 0, stream>>>(
        cur, K, wihP + WOFF[l], biasPF + (size_t)l * 2048, xgP);
    lstm_mx<<<16, 512, 0, stream>>>(xgP, wfrag + (size_t)l * 131072, nxt);
    cur = nxt;
    nxt = (nxt == xoutA) ? xoutB : xoutA;
  }

  ln_logits<<<ROWS, 64, 0, stream>>>(cur, ln_g, ln_b, lin_w, lin_b, out);
  crf_kernel<<<1, 256, 0, stream>>>(out, labels, attn_mask, crf_start, crf_end,
                                    crf_trans, out + (size_t)ROWS * LL);
}